// Round 12
// baseline (123.604 us; speedup 1.0000x reference)
//
#include <hip/hip_runtime.h>
#include <math.h>

// ---------------- constants (replicate reference fp32 op order) -------------
constexpr double dPI     = 3.14159265358979323846;
constexpr double dLAMBDA = 5.32e-7;
constexpr double dK      = 2.0 * dPI / dLAMBDA;
constexpr double dD1     = 0.05;
constexpr double dD2     = 0.05;
constexpr double dFOCAL  = dD1 * dD2 / (dD1 + dD2);      // 0.025

constexpr float C1F         = (float)(dK / (2.0 * dD1)); // input_phase coeff
constexpr float KFF         = (float)dK;
constexpr float TWO_FOCAL_F = (float)(2.0 * dFOCAL);     // 0.05
constexpr float TPF         = (float)(2.0 * dPI);
constexpr float INV_TPF     = (float)(1.0 / (2.0 * dPI));
constexpr float TPH         = (float)(2.0 * dPI);                     // 2pi hi
constexpr float TPL         = (float)(2.0 * dPI - (double)TPH);       // 2pi lo
constexpr float SENSOR_DF   = (float)(4096.0 * 2e-6);    // 8.192e-3
constexpr float ILAM2F      = (float)((1.0 / dLAMBDA) * (1.0 / dLAMBDA));
constexpr float D2F         = (float)dD2;
constexpr float PITCHF      = 2e-6f;
constexpr float SCALE       = 1.0f / 16777216.0f;        // 2^-24 = 1/(4096*4096)

// tridiag(1,4,1) inverse kernel constants
constexpr float TRI_R = -0.2679491924311227f;            // -2+sqrt(3)
constexpr float TRI_C = 0.2886751345948129f;             // 1/(2*sqrt(3))

// ---------------- packed complex types ----------------
typedef float    v2f __attribute__((ext_vector_type(2)));
typedef _Float16 h2f __attribute__((ext_vector_type(2)));

__device__ __forceinline__ v2f mkv(float a, float b){ v2f r; r.x=a; r.y=b; return r; }
__device__ __forceinline__ h2f toh(v2f v){ h2f h; h.x=(_Float16)v.x; h.y=(_Float16)v.y; return h; }
__device__ __forceinline__ v2f tof(h2f h){ return mkv((float)h.x, (float)h.y); }

// ---------- packed-FP32 VOP3P primitives (gfx90a+/gfx950) ----------
// complex held as (re=lo, im=hi) in a VGPR pair.
__device__ __forceinline__ v2f pkadd(v2f a, v2f b){
    v2f d;
    asm("v_pk_add_f32 %0, %1, %2" : "=v"(d) : "v"(a), "v"(b));
    return d;
}
__device__ __forceinline__ v2f pksub(v2f a, v2f b){
    v2f d;
    asm("v_pk_add_f32 %0, %1, %2 neg_lo:[0,1] neg_hi:[0,1]" : "=v"(d) : "v"(a), "v"(b));
    return d;
}
// a - i*b = (a.x + b.y, a.y - b.x)
__device__ __forceinline__ v2f addmi(v2f a, v2f b){
    v2f d;
    asm("v_pk_add_f32 %0, %1, %2 op_sel:[0,1] op_sel_hi:[1,0] neg_hi:[0,1]"
        : "=v"(d) : "v"(a), "v"(b));
    return d;
}
// a + i*b = (a.x - b.y, a.y + b.x)
__device__ __forceinline__ v2f addpi(v2f a, v2f b){
    v2f d;
    asm("v_pk_add_f32 %0, %1, %2 op_sel:[0,1] op_sel_hi:[1,0] neg_lo:[0,1]"
        : "=v"(d) : "v"(a), "v"(b));
    return d;
}
// complex multiply: 2 VOP3P ops (AMD canonical pattern)
__device__ __forceinline__ v2f cmul(v2f a, v2f b){
    v2f t, d;
    asm("v_pk_mul_f32 %0, %1, %2 op_sel:[0,0] op_sel_hi:[0,1]"
        : "=v"(t) : "v"(a), "v"(b));
    asm("v_pk_fma_f32 %0, %1, %2, %3 op_sel:[1,1,0] op_sel_hi:[1,0,1] neg_lo:[1,0,0]"
        : "=v"(d) : "v"(a), "v"(b), "v"(t));
    return d;
}
// a * conj(b)
__device__ __forceinline__ v2f cmulc(v2f a, v2f b){
    v2f t, d;
    asm("v_pk_mul_f32 %0, %1, %2 op_sel:[0,0] op_sel_hi:[0,1]"
        : "=v"(t) : "v"(a), "v"(b));
    asm("v_pk_fma_f32 %0, %1, %2, %3 op_sel:[1,1,0] op_sel_hi:[1,0,1] neg_hi:[0,0,1]"
        : "=v"(d) : "v"(a), "v"(b), "v"(t));
    return d;
}

__device__ __forceinline__ int digitrev12(int p){
    int r = __brev((unsigned)p) >> 20;
    return ((r & 0x555) << 1) | ((r >> 1) & 0x555);
}

// ---------------- radix-4 butterflies (DIF fwd / DIT inv) ----------------
__device__ __forceinline__ void bfly_fwd(v2f& A, v2f& B, v2f& C, v2f& D,
                                         v2f w1, v2f w2, v2f w3){
    v2f t0=pkadd(A,C), t1=pksub(A,C), t2=pkadd(B,D), t3=pksub(B,D);
    v2f y0=pkadd(t0,t2);
    v2f y1=addmi(t1,t3);
    v2f y2=pksub(t0,t2);
    v2f y3=addpi(t1,t3);
    A=y0; B=cmul(y1,w1); C=cmul(y2,w2); D=cmul(y3,w3);
}
__device__ __forceinline__ void bfly_fwd_nt(v2f& A, v2f& B, v2f& C, v2f& D){
    v2f t0=pkadd(A,C), t1=pksub(A,C), t2=pkadd(B,D), t3=pksub(B,D);
    A=pkadd(t0,t2);
    v2f y1=addmi(t1,t3);
    v2f y2=pksub(t0,t2);
    v2f y3=addpi(t1,t3);
    B=y1; C=y2; D=y3;
}
__device__ __forceinline__ void bfly_inv(v2f& A, v2f& B, v2f& C, v2f& D,
                                         v2f w1, v2f w2, v2f w3){
    v2f bb=cmulc(B,w1), cc=cmulc(C,w2), dd=cmulc(D,w3);
    v2f t0=pkadd(A,cc), t1=pksub(A,cc), t2=pkadd(bb,dd), t3=pksub(bb,dd);
    A=pkadd(t0,t2);
    B=addpi(t1,t3);
    C=pksub(t0,t2);
    D=addmi(t1,t3);
}
__device__ __forceinline__ void bfly_inv_nt(v2f& A, v2f& B, v2f& C, v2f& D){
    v2f t0=pkadd(A,C), t1=pksub(A,C), t2=pkadd(B,D), t3=pksub(B,D);
    A=pkadd(t0,t2);
    B=addpi(t1,t3);
    C=pksub(t0,t2);
    D=addmi(t1,t3);
}

// ---------------- register-fused stage pairs (table twiddles) ---------------
// ownership A (strided): r[q] = x[t + 256 q]
template<bool ZAD>
__device__ __forceinline__ void front_fwd(v2f* r, int t,
        const v2f* __restrict__ tw1, const v2f* __restrict__ tw2,
        const v2f* __restrict__ tw3){
#pragma unroll
    for (int j = 0; j < 4; ++j){
        int m = t + 256*j;
        v2f w1 = tw1[m], w2 = tw2[m], w3 = tw3[m];
        v2f y0, y1, y2, y3;
        if (ZAD){
            v2f Bv = r[j+4], Cv = r[j+8];          // A = D = 0
            v2f nC = mkv(-Cv.x, -Cv.y);
            y0 = pkadd(Cv, Bv);
            y1 = addmi(nC, Bv);
            y2 = pksub(Cv, Bv);
            y3 = addpi(nC, Bv);
        } else {
            v2f Av=r[j], Bv=r[j+4], Cv=r[j+8], Dv=r[j+12];
            v2f t0=pkadd(Av,Cv), t1=pksub(Av,Cv), t2=pkadd(Bv,Dv), t3=pksub(Bv,Dv);
            y0=pkadd(t0,t2);
            y1=addmi(t1,t3);
            y2=pksub(t0,t2);
            y3=addpi(t1,t3);
        }
        r[j]=y0; r[j+4]=cmul(y1,w1); r[j+8]=cmul(y2,w2); r[j+12]=cmul(y3,w3);
    }
    v2f w1 = tw1[1024+t], w2 = tw2[1024+t], w3 = tw3[1024+t];
#pragma unroll
    for (int k = 0; k < 4; ++k)
        bfly_fwd(r[4*k], r[4*k+1], r[4*k+2], r[4*k+3], w1, w2, w3);
}
// i5 full + i6 pruned to crop outputs (q6..q9)
__device__ __forceinline__ void back_inv_crop(v2f* r, int t,
        const v2f* __restrict__ tw1, const v2f* __restrict__ tw2,
        const v2f* __restrict__ tw3,
        v2f& o6, v2f& o7, v2f& o8, v2f& o9){
    v2f w1 = tw1[1024+t], w2 = tw2[1024+t], w3 = tw3[1024+t];
#pragma unroll
    for (int k = 0; k < 4; ++k)
        bfly_inv(r[4*k], r[4*k+1], r[4*k+2], r[4*k+3], w1, w2, w3);
    {   v2f u1=tw1[t], u2=tw2[t], u3=tw3[t];
        v2f bb=cmulc(r[4],u1), cc=cmulc(r[8],u2), dd=cmulc(r[12],u3);
        o8 = pksub(pkadd(r[0],cc), pkadd(bb,dd));
    }
    {   v2f u1=tw1[t+256], u2=tw2[t+256], u3=tw3[t+256];
        v2f bb=cmulc(r[5],u1), cc=cmulc(r[9],u2), dd=cmulc(r[13],u3);
        o9 = pksub(pkadd(r[1],cc), pkadd(bb,dd));
    }
    {   v2f u1=tw1[t+512], u2=tw2[t+512], u3=tw3[t+512];
        v2f bb=cmulc(r[6],u1), cc=cmulc(r[10],u2), dd=cmulc(r[14],u3);
        v2f t1=pksub(r[2],cc), t3=pksub(bb,dd);
        o6 = addpi(t1,t3);
    }
    {   v2f u1=tw1[t+768], u2=tw2[t+768], u3=tw3[t+768];
        v2f bb=cmulc(r[7],u1), cc=cmulc(r[11],u2), dd=cmulc(r[15],u3);
        v2f t1=pksub(r[3],cc), t3=pksub(bb,dd);
        o7 = addpi(t1,t3);
    }
}
__device__ __forceinline__ void mid_fwd(v2f* r, int c,
        const v2f* __restrict__ tw1, const v2f* __restrict__ tw2,
        const v2f* __restrict__ tw3){
#pragma unroll
    for (int h = 0; h < 4; ++h){
        int idx = 1280 + 16*h + c;
        bfly_fwd(r[h], r[h+4], r[h+8], r[h+12], tw1[idx], tw2[idx], tw3[idx]);
    }
    v2f w1 = tw1[1344+c], w2 = tw2[1344+c], w3 = tw3[1344+c];
#pragma unroll
    for (int j = 0; j < 4; ++j)
        bfly_fwd(r[4*j], r[4*j+1], r[4*j+2], r[4*j+3], w1, w2, w3);
}
__device__ __forceinline__ void mid_inv(v2f* r, int c,
        const v2f* __restrict__ tw1, const v2f* __restrict__ tw2,
        const v2f* __restrict__ tw3){
    v2f w1 = tw1[1344+c], w2 = tw2[1344+c], w3 = tw3[1344+c];
#pragma unroll
    for (int j = 0; j < 4; ++j)
        bfly_inv(r[4*j], r[4*j+1], r[4*j+2], r[4*j+3], w1, w2, w3);
#pragma unroll
    for (int h = 0; h < 4; ++h){
        int idx = 1280 + 16*h + c;
        bfly_inv(r[h], r[h+4], r[h+8], r[h+12], tw1[idx], tw2[idx], tw3[idx]);
    }
}
#define C16F 0.9238795325112867f
#define S16F 0.3826834323650898f
#define C8F  0.7071067811865476f
__device__ __forceinline__ void tail_fwd(v2f* r){
    const v2f W1[4] = {mkv(1,0),mkv(C16F,-S16F),mkv(C8F,-C8F),mkv(S16F,-C16F)};
    const v2f W2[4] = {mkv(1,0),mkv(C8F,-C8F),mkv(0,-1),mkv(-C8F,-C8F)};
    const v2f W3[4] = {mkv(1,0),mkv(S16F,-C16F),mkv(-C8F,-C8F),mkv(-C16F,S16F)};
    bfly_fwd_nt(r[0], r[4], r[8], r[12]);
#pragma unroll
    for (int m = 1; m < 4; ++m)
        bfly_fwd(r[m], r[m+4], r[m+8], r[m+12], W1[m], W2[m], W3[m]);
#pragma unroll
    for (int h = 0; h < 4; ++h)
        bfly_fwd_nt(r[4*h], r[4*h+1], r[4*h+2], r[4*h+3]);
}
__device__ __forceinline__ void head_inv(v2f* r){
    const v2f W1[4] = {mkv(1,0),mkv(C16F,-S16F),mkv(C8F,-C8F),mkv(S16F,-C16F)};
    const v2f W2[4] = {mkv(1,0),mkv(C8F,-C8F),mkv(0,-1),mkv(-C8F,-C8F)};
    const v2f W3[4] = {mkv(1,0),mkv(S16F,-C16F),mkv(-C8F,-C8F),mkv(-C16F,S16F)};
#pragma unroll
    for (int h = 0; h < 4; ++h)
        bfly_inv_nt(r[4*h], r[4*h+1], r[4*h+2], r[4*h+3]);
    bfly_inv_nt(r[0], r[4], r[8], r[12]);
#pragma unroll
    for (int m = 1; m < 4; ++m)
        bfly_inv(r[m], r[m+4], r[m+8], r[m+12], W1[m], W2[m], W3[m]);
}

// ---------------- LDS ownership exchanges (v2f, XOR-swizzled, 1 barrier) ----
__device__ __forceinline__ void x_strided_to_mid(v2f* r, v2f* lds, int t){
    int tsw = t ^ (t >> 4);
#pragma unroll
    for (int q = 0; q < 16; ++q) lds[256*q + tsw] = r[q];
    __syncthreads();
    int Bq = (t >> 4) * 256, c = t & 15;
#pragma unroll
    for (int g = 0; g < 16; ++g) r[g] = lds[Bq + 16*g + (c ^ g)];
}
__device__ __forceinline__ void x_mid_to_contig(v2f* r, v2f* lds, int t){
    int Bq = (t >> 4) * 256, c = t & 15;
#pragma unroll
    for (int g = 0; g < 16; ++g) lds[Bq + 16*g + (c ^ g)] = r[g];
    __syncthreads();
    int tl = t & 15, base = 16*t;
#pragma unroll
    for (int g = 0; g < 16; ++g) r[g] = lds[base + (g ^ tl)];
}
__device__ __forceinline__ void x_contig_to_mid(v2f* r, v2f* lds, int t){
    int tl = t & 15, base = 16*t;
#pragma unroll
    for (int g = 0; g < 16; ++g) lds[base + (g ^ tl)] = r[g];
    __syncthreads();
    int Bq = (t >> 4) * 256, c = t & 15;
#pragma unroll
    for (int g = 0; g < 16; ++g) r[g] = lds[Bq + 16*g + (c ^ g)];
}
__device__ __forceinline__ void x_mid_to_strided(v2f* r, v2f* lds, int t){
    int Bq = (t >> 4) * 256, c = t & 15;
#pragma unroll
    for (int g = 0; g < 16; ++g) lds[Bq + 16*g + (c ^ g)] = r[g];
    __syncthreads();
    int tsw = t ^ (t >> 4);
#pragma unroll
    for (int q = 0; q < 16; ++q) r[q] = lds[256*q + tsw];
}

// ------- setup: spline tridiag solve (blocks 0-7) + twiddles (blocks 8-13) --
__global__ __launch_bounds__(256) void k_setup(const float* __restrict__ p,
        float* __restrict__ Mv, v2f* __restrict__ tw1,
        v2f* __restrict__ tw2, v2f* __restrict__ tw3){
    int bid = blockIdx.x;
    int t = threadIdx.x;
    if (bid >= 8){
        int idx = (bid - 8) * 256 + t;
        if (idx >= 1360) return;
        int m, L;
        if (idx < 1024)      { m = idx;        L = 4096; }
        else if (idx < 1280) { m = idx - 1024; L = 1024; }
        else if (idx < 1344) { m = idx - 1280; L = 256;  }
        else                 { m = idx - 1344; L = 64;   }
        double ang = -2.0 * dPI * (double)m / (double)L;
        double s1, c1, s2, c2v, s3, c3;
        sincos(ang, &s1, &c1);
        sincos(2.0*ang, &s2, &c2v);
        sincos(3.0*ang, &s3, &c3);
        tw1[idx] = mkv((float)c1,  (float)s1);
        tw2[idx] = mkv((float)c2v, (float)s2);
        tw3[idx] = mkv((float)c3,  (float)s3);
        return;
    }
    __shared__ float sY[328];
    int B0 = bid * 256;
    for (int k = t; k < 324; k += 256){
        int jg = B0 - 32 + k;                 // Y[j] = j<1024 ? p[j>>1] : 0
        sY[k] = (jg >= 0 && jg < 1024) ? p[jg >> 1] : 0.0f;
    }
    __syncthreads();
    int i = B0 + t;
    if (i >= 2046) return;
    auto rhs = [&](int j) -> float {
        if (j < 0 || j >= 2046) return 0.0f;
        int l = j - B0 + 32;
        return 6.0f * (sY[l+2] - 2.0f*sY[l+1] + sY[l]);
    };
    float x = TRI_C * rhs(i);
    float wd = TRI_C;
    for (int d = 1; d <= 32; ++d){
        wd *= TRI_R;
        x += wd * (rhs(i-d) + rhs(i+d));
    }
    if (i < 48){
        float cA = 0.0f, wj = TRI_C;
        for (int j = 0; j < 32; ++j){ wj *= TRI_R; cA += wj * rhs(j); }
        float rp = 1.0f;
        for (int k = 0; k <= i; ++k) rp *= TRI_R;
        x -= cA * rp;
    }
    if (i >= 1998){
        float cB = 0.0f, wj = TRI_C;
        for (int j = 0; j < 32; ++j){ wj *= TRI_R; cB += wj * rhs(2045 - j); }
        float rp = 1.0f;
        for (int k = 0; k < 2046 - i; ++k) rp *= TRI_R;
        x -= cB * rp;
    }
    Mv[i+1] = x;
    if (i == 0)    Mv[0]    = 0.0f;
    if (i == 2045) Mv[2047] = 0.0f;
}

// ---------------- pass 1: field build + fwd row FFT (fp16 out) --------------
__global__ __launch_bounds__(256) void k_pass1(const float* __restrict__ p,
        const float* __restrict__ Mv,
        const v2f* __restrict__ tw1, const v2f* __restrict__ tw2,
        const v2f* __restrict__ tw3, h2f* __restrict__ F1){
    __shared__ v2f lds[4096];
    int t = threadIdx.x;
    int row = blockIdx.x;                 // y = 1024 + row
    v2f r[16];
    int y = 1024 + row;
    int iy = row;
    int a = (iy < 1024) ? (1023 - iy) : (iy - 1024);
    float fy = PITCHF * (float)(y - 2048);
    float cy2 = fy * fy;
    float af = (float)a + 0.5f;
#pragma unroll
    for (int q = 4; q < 12; ++q){
        int x = t + 256*q;                // in [1024, 3072)
        int ix = x - 1024;
        int b = (ix < 1024) ? (1023 - ix) : (ix - 1024);
        float bf = (float)b + 0.5f;
        float rq = sqrtf(af*af + bf*bf);
        int ind = (int)rq; if (ind > 2046) ind = 2046;
        float tt = rq - (float)ind;
        float y0v = (ind < 1024) ? p[ind >> 1] : 0.0f;       // Y[ind]
        float y1v = (ind + 1 < 1024) ? p[(ind + 1) >> 1] : 0.0f; // Y[ind+1]
        float m0 = Mv[ind], m1 = Mv[ind+1];
        float bb = (y1v - y0v) - (2.0f*m0 + m1) / 6.0f;
        float bias = y0v + tt*(bb + tt*(m0/2.0f + tt*(m1-m0)/6.0f));
        float fx = PITCHF * (float)(x - 2048);
        float r2 = fx*fx + cy2;
        float ip = C1F * r2;
        float lp = -((KFF * r2) / TWO_FOCAL_F);
        float sp = ip + lp + bias;
        float fv = sp * INV_TPF;                     // phase in revolutions
        float fr = fv - floorf(fv);                  // [0,1)
        float sn = __builtin_amdgcn_sinf(fr);
        float cs = __builtin_amdgcn_cosf(fr);
        r[q] = mkv(cs, sn);
    }
    front_fwd<true>(r, t, tw1, tw2, tw3);
    x_strided_to_mid(r, lds, t);
    mid_fwd(r, t & 15, tw1, tw2, tw3);
    x_mid_to_contig(r, lds, t);
    tail_fwd(r);
    size_t base = (size_t)row * 4096;
#pragma unroll
    for (int g = 0; g < 16; ++g)
        F1[base + 256*g + t] = toh(r[g]);  // coalesced per g
}

// ------- tiled 4-byte transpose (h2f as uint), uint2-vectorized -------------
__global__ __launch_bounds__(256) void k_transpose_h(const unsigned* __restrict__ in,
                                                     unsigned* __restrict__ out,
                                                     int H, int W){
    __shared__ unsigned tile[32][33];
    int bx = blockIdx.x * 32, by = blockIdx.y * 32;
    int tx = threadIdx.x, ty = threadIdx.y;   // (16,16)
#pragma unroll
    for (int k = 0; k < 32; k += 16){
        int rr = by + ty + k, cc = bx + 2*tx;
        if (rr < H && cc < W){
            uint2 v = *(const uint2*)&in[(size_t)rr * W + cc];
            tile[ty + k][2*tx]     = v.x;
            tile[ty + k][2*tx + 1] = v.y;
        }
    }
    __syncthreads();
#pragma unroll
    for (int k = 0; k < 32; k += 16){
        int rr = bx + ty + k, cc = by + 2*tx;
        if (rr < W && cc < H){
            uint2 v = make_uint2(tile[2*tx][ty + k], tile[2*tx + 1][ty + k]);
            *(uint2*)&out[(size_t)rr * H + cc] = v;
        }
    }
}

// ------- pass 2: 512 threads, 2 columns (one per 256-thread half) -----------
__global__ __launch_bounds__(512) void k_pass2(const h2f* __restrict__ F1T,
        const v2f* __restrict__ tw1, const v2f* __restrict__ tw2,
        const v2f* __restrict__ tw3, h2f* __restrict__ GT){
    __shared__ v2f lds_all[8192];         // 64 KiB: 32 KiB per half
    int tid  = threadIdx.x;
    int half = tid >> 8;
    int t    = tid & 255;
    v2f* lds = lds_all + half * 4096;
    int cp = 2 * blockIdx.x + half;       // c' column index
    v2f r[16];
    size_t base = (size_t)cp * 2048;
#pragma unroll
    for (int q = 4; q < 12; ++q)
        r[q] = tof(F1T[base + t + 256*(q-4)]); // y = t + 256 q, nonzero half
    front_fwd<true>(r, t, tw1, tw2, tw3);
    x_strided_to_mid(r, lds, t);
    mid_fwd(r, t & 15, tw1, tw2, tw3);
    x_mid_to_contig(r, lds, t);
    tail_fwd(r);
    // ---- H multiply in digit-reversed frequency domain (incl. 1/N^2) ----
    int pcol = ((cp & 255) << 4) | (cp >> 8);
    int kx = digitrev12(pcol);
    int kxs = (kx + 2048) & 4095;
    float fxv = ((float)(kxs + 1) - 2048.0f) / SENSOR_DF;
    float fx2 = fxv * fxv;
    int rt = __brev((unsigned)t) >> 24;
    rt = ((rt & 0x55) << 1) | ((rt >> 1) & 0x55);   // 4-digit base-4 reversal of t
#pragma unroll
    for (int g = 0; g < 16; ++g){
        const int rg = ((g & 3) << 2) | (g >> 2);
        int ky = rg * 256 + rt;                      // digitrev12(16 t + g)
        int kys = (ky + 2048) & 4095;
        float fyv = ((float)(kys + 1) - 2048.0f) / SENSOR_DF;
        float arg = ILAM2F - fx2 - fyv*fyv;
        arg = fmaxf(arg, 0.0f);
        float w1v = sqrtf(arg);
        float Hp = (TPF * w1v) * D2F;                // exact ref fp32 value
        float v  = Hp * INV_TPF;
        float nn = rintf(v);
        float rr = fmaf(nn, -TPH, Hp);
        rr       = fmaf(nn, -TPL, rr);
        float rev = rr * INV_TPF;                    // in [-0.5, 0.5]
        float sn = __builtin_amdgcn_sinf(rev);
        float cs = __builtin_amdgcn_cosf(rev);
        r[g] = cmul(r[g], mkv(cs * SCALE, sn * SCALE));
    }
    head_inv(r);
    x_contig_to_mid(r, lds, t);
    mid_inv(r, t & 15, tw1, tw2, tw3);
    x_mid_to_strided(r, lds, t);
    v2f o6, o7, o8, o9;
    back_inv_crop(r, t, tw1, tw2, tw3, o6, o7, o8, o9);
    size_t ob = (size_t)cp * 728;
    // crop y in [1685, 2413): idx = t + 256q - 1685
    if (t >= 149) GT[ob + t - 149] = toh(o6);
    GT[ob + t + 107] = toh(o7);
    GT[ob + t + 363] = toh(o8);
    if (t < 109)  GT[ob + t + 619] = toh(o9);
}

// ---------------- pass 3: inv row FFT on crop rows, |.|^2 -------------------
__global__ __launch_bounds__(256) void k_pass3(const h2f* __restrict__ G,
        float* __restrict__ out, float* __restrict__ partials,
        const v2f* __restrict__ tw1, const v2f* __restrict__ tw2,
        const v2f* __restrict__ tw3){
    __shared__ v2f lds[4096];
    int t = threadIdx.x;
    int row = blockIdx.x;
    v2f r[16];
    size_t base = (size_t)row * 4096;
#pragma unroll
    for (int g = 0; g < 16; ++g)
        r[g] = tof(G[base + 256*g + t]);  // c' = 256 g + t <-> p = 16 t + g
    head_inv(r);
    x_contig_to_mid(r, lds, t);
    mid_inv(r, t & 15, tw1, tw2, tw3);
    x_mid_to_strided(r, lds, t);
    v2f o6, o7, o8, o9;
    back_inv_crop(r, t, tw1, tw2, tw3, o6, o7, o8, o9);
    float lsum = 0.0f;
    size_t ob = (size_t)row * 728;
    if (t >= 149){ float I = o6.x*o6.x + o6.y*o6.y; out[ob + t - 149] = I; lsum += I; }
    { float I = o7.x*o7.x + o7.y*o7.y; out[ob + t + 107] = I; lsum += I; }
    { float I = o8.x*o8.x + o8.y*o8.y; out[ob + t + 363] = I; lsum += I; }
    if (t < 109){ float I = o9.x*o9.x + o9.y*o9.y; out[ob + t + 619] = I; lsum += I; }
    __syncthreads();                       // all exchange reads done
    float* red = (float*)lds;
    red[t] = lsum;
    __syncthreads();
    for (int k2 = 128; k2 > 0; k2 >>= 1){
        if (t < k2) red[t] += red[t + k2];
        __syncthreads();
    }
    if (t == 0) partials[row] = red[0];
}

// ---------------- normalize (per-block redundant deterministic reduce) ------
__global__ __launch_bounds__(256) void k_norm(float* __restrict__ out,
                                              const float* __restrict__ partials,
                                              int n){
    __shared__ float red[256];
    int t = threadIdx.x;
    float s = 0.0f;
    for (int i = t; i < 728; i += 256) s += partials[i];
    red[t] = s;
    __syncthreads();
    for (int k = 128; k > 0; k >>= 1){
        if (t < k) red[t] += red[t + k];
        __syncthreads();
    }
    float total = red[0];
    int i = blockIdx.x * 256 + t;
    if (i < n) out[i] = out[i] / total;
}

// ---------------- launch ----------------
extern "C" void kernel_launch(void* const* d_in, const int* in_sizes, int n_in,
                              void* d_out, int out_size, void* d_ws, size_t ws_size,
                              hipStream_t stream) {
    const float* p   = (const float*)d_in[0];
    float*       out = (float*)d_out;
    char*        ws  = (char*)d_ws;

    float* Mv       = (float*)(ws + 8192);         // 2048 f
    float* partials = (float*)(ws + 16384);        // 728 f
    v2f*   tw1      = (v2f*)(ws + 24576);          // 1360 c (fp32)
    v2f*   tw2      = (v2f*)(ws + 40960);
    v2f*   tw3      = (v2f*)(ws + 57344);

    const size_t BIG = (size_t)64 * 1024 * 1024;
    h2f* F1  = (h2f*)(ws + (1 << 20));             // [2048][4096] fp16c, 32MB
    h2f* F1T = (h2f*)(ws + (1 << 20) + BIG);       // [4096][2048] fp16c
    h2f* GT  = F1;                                  // reuse: [4096][728]
    h2f* G   = F1T;                                 // reuse: [728][4096]

    k_setup<<<14, 256, 0, stream>>>(p, Mv, tw1, tw2, tw3);
    k_pass1<<<2048, 256, 0, stream>>>(p, Mv, tw1, tw2, tw3, F1);
    k_transpose_h<<<dim3(128, 64), dim3(16, 16), 0, stream>>>((const unsigned*)F1, (unsigned*)F1T, 2048, 4096);
    k_pass2<<<2048, 512, 0, stream>>>(F1T, tw1, tw2, tw3, GT);
    k_transpose_h<<<dim3(23, 128), dim3(16, 16), 0, stream>>>((const unsigned*)GT, (unsigned*)G, 4096, 728);
    k_pass3<<<728, 256, 0, stream>>>(G, out, partials, tw1, tw2, tw3);
    int n = out_size;
    k_norm<<<(n + 255) / 256, 256, 0, stream>>>(out, partials, n);
}

// Round 13
// 114.383 us; speedup vs baseline: 1.0806x; 1.0806x over previous
//
#include <hip/hip_runtime.h>
#include <math.h>

// ---------------- constants (replicate reference fp32 op order) -------------
constexpr double dPI     = 3.14159265358979323846;
constexpr double dLAMBDA = 5.32e-7;
constexpr double dK      = 2.0 * dPI / dLAMBDA;
constexpr double dD1     = 0.05;
constexpr double dD2     = 0.05;
constexpr double dFOCAL  = dD1 * dD2 / (dD1 + dD2);      // 0.025

constexpr float C1F         = (float)(dK / (2.0 * dD1)); // input_phase coeff
constexpr float KFF         = (float)dK;
constexpr float TWO_FOCAL_F = (float)(2.0 * dFOCAL);     // 0.05
constexpr float TPF         = (float)(2.0 * dPI);
constexpr float INV_TPF     = (float)(1.0 / (2.0 * dPI));
constexpr float TPH         = (float)(2.0 * dPI);                     // 2pi hi
constexpr float TPL         = (float)(2.0 * dPI - (double)TPH);       // 2pi lo
constexpr float SENSOR_DF   = (float)(4096.0 * 2e-6);    // 8.192e-3
constexpr float ILAM2F      = (float)((1.0 / dLAMBDA) * (1.0 / dLAMBDA));
constexpr float D2F         = (float)dD2;
constexpr float PITCHF      = 2e-6f;
constexpr float SCALE       = 1.0f / 16777216.0f;        // 2^-24 = 1/(4096*4096)

// tridiag(1,4,1) inverse kernel constants
constexpr float TRI_R = -0.2679491924311227f;            // -2+sqrt(3)
constexpr float TRI_C = 0.2886751345948129f;             // 1/(2*sqrt(3))

// ---------------- packed complex types ----------------
typedef float    v2f __attribute__((ext_vector_type(2)));
typedef _Float16 h2f __attribute__((ext_vector_type(2)));

__device__ __forceinline__ v2f mkv(float a, float b){ v2f r; r.x=a; r.y=b; return r; }
__device__ __forceinline__ h2f toh(v2f v){ h2f h; h.x=(_Float16)v.x; h.y=(_Float16)v.y; return h; }
__device__ __forceinline__ v2f tof(h2f h){ return mkv((float)h.x, (float)h.y); }

// ---------- packed-FP32 VOP3P primitives (gfx90a+/gfx950) ----------
// complex held as (re=lo, im=hi) in a VGPR pair.
__device__ __forceinline__ v2f pkadd(v2f a, v2f b){
    v2f d;
    asm("v_pk_add_f32 %0, %1, %2" : "=v"(d) : "v"(a), "v"(b));
    return d;
}
__device__ __forceinline__ v2f pksub(v2f a, v2f b){
    v2f d;
    asm("v_pk_add_f32 %0, %1, %2 neg_lo:[0,1] neg_hi:[0,1]" : "=v"(d) : "v"(a), "v"(b));
    return d;
}
// a - i*b = (a.x + b.y, a.y - b.x)
__device__ __forceinline__ v2f addmi(v2f a, v2f b){
    v2f d;
    asm("v_pk_add_f32 %0, %1, %2 op_sel:[0,1] op_sel_hi:[1,0] neg_hi:[0,1]"
        : "=v"(d) : "v"(a), "v"(b));
    return d;
}
// a + i*b = (a.x - b.y, a.y + b.x)
__device__ __forceinline__ v2f addpi(v2f a, v2f b){
    v2f d;
    asm("v_pk_add_f32 %0, %1, %2 op_sel:[0,1] op_sel_hi:[1,0] neg_lo:[0,1]"
        : "=v"(d) : "v"(a), "v"(b));
    return d;
}
// complex multiply: 2 VOP3P ops (AMD canonical pattern)
__device__ __forceinline__ v2f cmul(v2f a, v2f b){
    v2f t, d;
    asm("v_pk_mul_f32 %0, %1, %2 op_sel:[0,0] op_sel_hi:[0,1]"
        : "=v"(t) : "v"(a), "v"(b));
    asm("v_pk_fma_f32 %0, %1, %2, %3 op_sel:[1,1,0] op_sel_hi:[1,0,1] neg_lo:[1,0,0]"
        : "=v"(d) : "v"(a), "v"(b), "v"(t));
    return d;
}
// a * conj(b)
__device__ __forceinline__ v2f cmulc(v2f a, v2f b){
    v2f t, d;
    asm("v_pk_mul_f32 %0, %1, %2 op_sel:[0,0] op_sel_hi:[0,1]"
        : "=v"(t) : "v"(a), "v"(b));
    asm("v_pk_fma_f32 %0, %1, %2, %3 op_sel:[1,1,0] op_sel_hi:[1,0,1] neg_hi:[0,0,1]"
        : "=v"(d) : "v"(a), "v"(b), "v"(t));
    return d;
}

__device__ __forceinline__ int digitrev12(int p){
    int r = __brev((unsigned)p) >> 20;
    return ((r & 0x555) << 1) | ((r >> 1) & 0x555);
}

// ---------------- radix-4 butterflies (DIF fwd / DIT inv) ----------------
__device__ __forceinline__ void bfly_fwd(v2f& A, v2f& B, v2f& C, v2f& D,
                                         v2f w1, v2f w2, v2f w3){
    v2f t0=pkadd(A,C), t1=pksub(A,C), t2=pkadd(B,D), t3=pksub(B,D);
    v2f y0=pkadd(t0,t2);
    v2f y1=addmi(t1,t3);
    v2f y2=pksub(t0,t2);
    v2f y3=addpi(t1,t3);
    A=y0; B=cmul(y1,w1); C=cmul(y2,w2); D=cmul(y3,w3);
}
__device__ __forceinline__ void bfly_fwd_nt(v2f& A, v2f& B, v2f& C, v2f& D){
    v2f t0=pkadd(A,C), t1=pksub(A,C), t2=pkadd(B,D), t3=pksub(B,D);
    A=pkadd(t0,t2);
    v2f y1=addmi(t1,t3);
    v2f y2=pksub(t0,t2);
    v2f y3=addpi(t1,t3);
    B=y1; C=y2; D=y3;
}
__device__ __forceinline__ void bfly_inv(v2f& A, v2f& B, v2f& C, v2f& D,
                                         v2f w1, v2f w2, v2f w3){
    v2f bb=cmulc(B,w1), cc=cmulc(C,w2), dd=cmulc(D,w3);
    v2f t0=pkadd(A,cc), t1=pksub(A,cc), t2=pkadd(bb,dd), t3=pksub(bb,dd);
    A=pkadd(t0,t2);
    B=addpi(t1,t3);
    C=pksub(t0,t2);
    D=addmi(t1,t3);
}
__device__ __forceinline__ void bfly_inv_nt(v2f& A, v2f& B, v2f& C, v2f& D){
    v2f t0=pkadd(A,C), t1=pksub(A,C), t2=pkadd(B,D), t3=pksub(B,D);
    A=pkadd(t0,t2);
    B=addpi(t1,t3);
    C=pksub(t0,t2);
    D=addmi(t1,t3);
}

// ---------------- register-fused stage pairs (table twiddles) ---------------
// ownership A (strided): r[q] = x[t + 256 q]
template<bool ZAD>
__device__ __forceinline__ void front_fwd(v2f* r, int t,
        const v2f* __restrict__ tw1, const v2f* __restrict__ tw2,
        const v2f* __restrict__ tw3){
#pragma unroll
    for (int j = 0; j < 4; ++j){
        int m = t + 256*j;
        v2f w1 = tw1[m], w2 = tw2[m], w3 = tw3[m];
        v2f y0, y1, y2, y3;
        if (ZAD){
            v2f Bv = r[j+4], Cv = r[j+8];          // A = D = 0
            v2f nC = mkv(-Cv.x, -Cv.y);
            y0 = pkadd(Cv, Bv);
            y1 = addmi(nC, Bv);
            y2 = pksub(Cv, Bv);
            y3 = addpi(nC, Bv);
        } else {
            v2f Av=r[j], Bv=r[j+4], Cv=r[j+8], Dv=r[j+12];
            v2f t0=pkadd(Av,Cv), t1=pksub(Av,Cv), t2=pkadd(Bv,Dv), t3=pksub(Bv,Dv);
            y0=pkadd(t0,t2);
            y1=addmi(t1,t3);
            y2=pksub(t0,t2);
            y3=addpi(t1,t3);
        }
        r[j]=y0; r[j+4]=cmul(y1,w1); r[j+8]=cmul(y2,w2); r[j+12]=cmul(y3,w3);
    }
    v2f w1 = tw1[1024+t], w2 = tw2[1024+t], w3 = tw3[1024+t];
#pragma unroll
    for (int k = 0; k < 4; ++k)
        bfly_fwd(r[4*k], r[4*k+1], r[4*k+2], r[4*k+3], w1, w2, w3);
}
// i5 full + i6 pruned to crop outputs (q6..q9)
__device__ __forceinline__ void back_inv_crop(v2f* r, int t,
        const v2f* __restrict__ tw1, const v2f* __restrict__ tw2,
        const v2f* __restrict__ tw3,
        v2f& o6, v2f& o7, v2f& o8, v2f& o9){
    v2f w1 = tw1[1024+t], w2 = tw2[1024+t], w3 = tw3[1024+t];
#pragma unroll
    for (int k = 0; k < 4; ++k)
        bfly_inv(r[4*k], r[4*k+1], r[4*k+2], r[4*k+3], w1, w2, w3);
    {   v2f u1=tw1[t], u2=tw2[t], u3=tw3[t];
        v2f bb=cmulc(r[4],u1), cc=cmulc(r[8],u2), dd=cmulc(r[12],u3);
        o8 = pksub(pkadd(r[0],cc), pkadd(bb,dd));
    }
    {   v2f u1=tw1[t+256], u2=tw2[t+256], u3=tw3[t+256];
        v2f bb=cmulc(r[5],u1), cc=cmulc(r[9],u2), dd=cmulc(r[13],u3);
        o9 = pksub(pkadd(r[1],cc), pkadd(bb,dd));
    }
    {   v2f u1=tw1[t+512], u2=tw2[t+512], u3=tw3[t+512];
        v2f bb=cmulc(r[6],u1), cc=cmulc(r[10],u2), dd=cmulc(r[14],u3);
        v2f t1=pksub(r[2],cc), t3=pksub(bb,dd);
        o6 = addpi(t1,t3);
    }
    {   v2f u1=tw1[t+768], u2=tw2[t+768], u3=tw3[t+768];
        v2f bb=cmulc(r[7],u1), cc=cmulc(r[11],u2), dd=cmulc(r[15],u3);
        v2f t1=pksub(r[3],cc), t3=pksub(bb,dd);
        o7 = addpi(t1,t3);
    }
}
__device__ __forceinline__ void mid_fwd(v2f* r, int c,
        const v2f* __restrict__ tw1, const v2f* __restrict__ tw2,
        const v2f* __restrict__ tw3){
#pragma unroll
    for (int h = 0; h < 4; ++h){
        int idx = 1280 + 16*h + c;
        bfly_fwd(r[h], r[h+4], r[h+8], r[h+12], tw1[idx], tw2[idx], tw3[idx]);
    }
    v2f w1 = tw1[1344+c], w2 = tw2[1344+c], w3 = tw3[1344+c];
#pragma unroll
    for (int j = 0; j < 4; ++j)
        bfly_fwd(r[4*j], r[4*j+1], r[4*j+2], r[4*j+3], w1, w2, w3);
}
__device__ __forceinline__ void mid_inv(v2f* r, int c,
        const v2f* __restrict__ tw1, const v2f* __restrict__ tw2,
        const v2f* __restrict__ tw3){
    v2f w1 = tw1[1344+c], w2 = tw2[1344+c], w3 = tw3[1344+c];
#pragma unroll
    for (int j = 0; j < 4; ++j)
        bfly_inv(r[4*j], r[4*j+1], r[4*j+2], r[4*j+3], w1, w2, w3);
#pragma unroll
    for (int h = 0; h < 4; ++h){
        int idx = 1280 + 16*h + c;
        bfly_inv(r[h], r[h+4], r[h+8], r[h+12], tw1[idx], tw2[idx], tw3[idx]);
    }
}
#define C16F 0.9238795325112867f
#define S16F 0.3826834323650898f
#define C8F  0.7071067811865476f
__device__ __forceinline__ void tail_fwd(v2f* r){
    const v2f W1[4] = {mkv(1,0),mkv(C16F,-S16F),mkv(C8F,-C8F),mkv(S16F,-C16F)};
    const v2f W2[4] = {mkv(1,0),mkv(C8F,-C8F),mkv(0,-1),mkv(-C8F,-C8F)};
    const v2f W3[4] = {mkv(1,0),mkv(S16F,-C16F),mkv(-C8F,-C8F),mkv(-C16F,S16F)};
    bfly_fwd_nt(r[0], r[4], r[8], r[12]);
#pragma unroll
    for (int m = 1; m < 4; ++m)
        bfly_fwd(r[m], r[m+4], r[m+8], r[m+12], W1[m], W2[m], W3[m]);
#pragma unroll
    for (int h = 0; h < 4; ++h)
        bfly_fwd_nt(r[4*h], r[4*h+1], r[4*h+2], r[4*h+3]);
}
__device__ __forceinline__ void head_inv(v2f* r){
    const v2f W1[4] = {mkv(1,0),mkv(C16F,-S16F),mkv(C8F,-C8F),mkv(S16F,-C16F)};
    const v2f W2[4] = {mkv(1,0),mkv(C8F,-C8F),mkv(0,-1),mkv(-C8F,-C8F)};
    const v2f W3[4] = {mkv(1,0),mkv(S16F,-C16F),mkv(-C8F,-C8F),mkv(-C16F,S16F)};
#pragma unroll
    for (int h = 0; h < 4; ++h)
        bfly_inv_nt(r[4*h], r[4*h+1], r[4*h+2], r[4*h+3]);
    bfly_inv_nt(r[0], r[4], r[8], r[12]);
#pragma unroll
    for (int m = 1; m < 4; ++m)
        bfly_inv(r[m], r[m+4], r[m+8], r[m+12], W1[m], W2[m], W3[m]);
}

// ---------------- LDS ownership exchanges (v2f, XOR-swizzled, 1 barrier) ----
__device__ __forceinline__ void x_strided_to_mid(v2f* r, v2f* lds, int t){
    int tsw = t ^ (t >> 4);
#pragma unroll
    for (int q = 0; q < 16; ++q) lds[256*q + tsw] = r[q];
    __syncthreads();
    int Bq = (t >> 4) * 256, c = t & 15;
#pragma unroll
    for (int g = 0; g < 16; ++g) r[g] = lds[Bq + 16*g + (c ^ g)];
}
__device__ __forceinline__ void x_mid_to_contig(v2f* r, v2f* lds, int t){
    int Bq = (t >> 4) * 256, c = t & 15;
#pragma unroll
    for (int g = 0; g < 16; ++g) lds[Bq + 16*g + (c ^ g)] = r[g];
    __syncthreads();
    int tl = t & 15, base = 16*t;
#pragma unroll
    for (int g = 0; g < 16; ++g) r[g] = lds[base + (g ^ tl)];
}
__device__ __forceinline__ void x_contig_to_mid(v2f* r, v2f* lds, int t){
    int tl = t & 15, base = 16*t;
#pragma unroll
    for (int g = 0; g < 16; ++g) lds[base + (g ^ tl)] = r[g];
    __syncthreads();
    int Bq = (t >> 4) * 256, c = t & 15;
#pragma unroll
    for (int g = 0; g < 16; ++g) r[g] = lds[Bq + 16*g + (c ^ g)];
}
__device__ __forceinline__ void x_mid_to_strided(v2f* r, v2f* lds, int t){
    int Bq = (t >> 4) * 256, c = t & 15;
#pragma unroll
    for (int g = 0; g < 16; ++g) lds[Bq + 16*g + (c ^ g)] = r[g];
    __syncthreads();
    int tsw = t ^ (t >> 4);
#pragma unroll
    for (int q = 0; q < 16; ++q) r[q] = lds[256*q + tsw];
}

// ------- setup: spline tridiag solve (blocks 0-7) + twiddles (blocks 8-13) --
__global__ __launch_bounds__(256) void k_setup(const float* __restrict__ p,
        float* __restrict__ Mv, v2f* __restrict__ tw1,
        v2f* __restrict__ tw2, v2f* __restrict__ tw3){
    int bid = blockIdx.x;
    int t = threadIdx.x;
    if (bid >= 8){
        int idx = (bid - 8) * 256 + t;
        if (idx >= 1360) return;
        int m, L;
        if (idx < 1024)      { m = idx;        L = 4096; }
        else if (idx < 1280) { m = idx - 1024; L = 1024; }
        else if (idx < 1344) { m = idx - 1280; L = 256;  }
        else                 { m = idx - 1344; L = 64;   }
        double ang = -2.0 * dPI * (double)m / (double)L;
        double s1, c1, s2, c2v, s3, c3;
        sincos(ang, &s1, &c1);
        sincos(2.0*ang, &s2, &c2v);
        sincos(3.0*ang, &s3, &c3);
        tw1[idx] = mkv((float)c1,  (float)s1);
        tw2[idx] = mkv((float)c2v, (float)s2);
        tw3[idx] = mkv((float)c3,  (float)s3);
        return;
    }
    __shared__ float sY[328];
    int B0 = bid * 256;
    for (int k = t; k < 324; k += 256){
        int jg = B0 - 32 + k;                 // Y[j] = j<1024 ? p[j>>1] : 0
        sY[k] = (jg >= 0 && jg < 1024) ? p[jg >> 1] : 0.0f;
    }
    __syncthreads();
    int i = B0 + t;
    if (i >= 2046) return;
    auto rhs = [&](int j) -> float {
        if (j < 0 || j >= 2046) return 0.0f;
        int l = j - B0 + 32;
        return 6.0f * (sY[l+2] - 2.0f*sY[l+1] + sY[l]);
    };
    float x = TRI_C * rhs(i);
    float wd = TRI_C;
    for (int d = 1; d <= 32; ++d){
        wd *= TRI_R;
        x += wd * (rhs(i-d) + rhs(i+d));
    }
    if (i < 48){
        float cA = 0.0f, wj = TRI_C;
        for (int j = 0; j < 32; ++j){ wj *= TRI_R; cA += wj * rhs(j); }
        float rp = 1.0f;
        for (int k = 0; k <= i; ++k) rp *= TRI_R;
        x -= cA * rp;
    }
    if (i >= 1998){
        float cB = 0.0f, wj = TRI_C;
        for (int j = 0; j < 32; ++j){ wj *= TRI_R; cB += wj * rhs(2045 - j); }
        float rp = 1.0f;
        for (int k = 0; k < 2046 - i; ++k) rp *= TRI_R;
        x -= cB * rp;
    }
    Mv[i+1] = x;
    if (i == 0)    Mv[0]    = 0.0f;
    if (i == 2045) Mv[2047] = 0.0f;
}

// ---------------- pass 1: field build + fwd row FFT (fp16 out) --------------
__global__ __launch_bounds__(256) void k_pass1(const float* __restrict__ p,
        const float* __restrict__ Mv,
        const v2f* __restrict__ tw1, const v2f* __restrict__ tw2,
        const v2f* __restrict__ tw3, h2f* __restrict__ F1){
    __shared__ v2f lds[4096];
    int t = threadIdx.x;
    int row = blockIdx.x;                 // y = 1024 + row
    v2f r[16];
    int y = 1024 + row;
    int iy = row;
    int a = (iy < 1024) ? (1023 - iy) : (iy - 1024);
    float fy = PITCHF * (float)(y - 2048);
    float cy2 = fy * fy;
    float af = (float)a + 0.5f;
#pragma unroll
    for (int q = 4; q < 12; ++q){
        int x = t + 256*q;                // in [1024, 3072)
        int ix = x - 1024;
        int b = (ix < 1024) ? (1023 - ix) : (ix - 1024);
        float bf = (float)b + 0.5f;
        float rq = sqrtf(af*af + bf*bf);
        int ind = (int)rq; if (ind > 2046) ind = 2046;
        float tt = rq - (float)ind;
        float y0v = (ind < 1024) ? p[ind >> 1] : 0.0f;       // Y[ind]
        float y1v = (ind + 1 < 1024) ? p[(ind + 1) >> 1] : 0.0f; // Y[ind+1]
        float m0 = Mv[ind], m1 = Mv[ind+1];
        float bb = (y1v - y0v) - (2.0f*m0 + m1) / 6.0f;
        float bias = y0v + tt*(bb + tt*(m0/2.0f + tt*(m1-m0)/6.0f));
        float fx = PITCHF * (float)(x - 2048);
        float r2 = fx*fx + cy2;
        float ip = C1F * r2;
        float lp = -((KFF * r2) / TWO_FOCAL_F);
        float sp = ip + lp + bias;
        float fv = sp * INV_TPF;                     // phase in revolutions
        float fr = fv - floorf(fv);                  // [0,1)
        float sn = __builtin_amdgcn_sinf(fr);
        float cs = __builtin_amdgcn_cosf(fr);
        r[q] = mkv(cs, sn);
    }
    front_fwd<true>(r, t, tw1, tw2, tw3);
    x_strided_to_mid(r, lds, t);
    mid_fwd(r, t & 15, tw1, tw2, tw3);
    x_mid_to_contig(r, lds, t);
    tail_fwd(r);
    size_t base = (size_t)row * 4096;
#pragma unroll
    for (int g = 0; g < 16; ++g)
        F1[base + 256*g + t] = toh(r[g]);  // coalesced per g
}

// ------- tiled 4-byte transpose (h2f as uint), uint2-vectorized -------------
__global__ __launch_bounds__(256) void k_transpose_h(const unsigned* __restrict__ in,
                                                     unsigned* __restrict__ out,
                                                     int H, int W){
    __shared__ unsigned tile[32][33];
    int bx = blockIdx.x * 32, by = blockIdx.y * 32;
    int tx = threadIdx.x, ty = threadIdx.y;   // (16,16)
#pragma unroll
    for (int k = 0; k < 32; k += 16){
        int rr = by + ty + k, cc = bx + 2*tx;
        if (rr < H && cc < W){
            uint2 v = *(const uint2*)&in[(size_t)rr * W + cc];
            tile[ty + k][2*tx]     = v.x;
            tile[ty + k][2*tx + 1] = v.y;
        }
    }
    __syncthreads();
#pragma unroll
    for (int k = 0; k < 32; k += 16){
        int rr = bx + ty + k, cc = by + 2*tx;
        if (rr < W && cc < H){
            uint2 v = make_uint2(tile[2*tx][ty + k], tile[2*tx + 1][ty + k]);
            *(uint2*)&out[(size_t)rr * H + cc] = v;
        }
    }
}

// ---------------- pass 2: col fwd FFT + H + col inv FFT, crop ---------------
__global__ __launch_bounds__(256, 8) void k_pass2(const h2f* __restrict__ F1T,
        const v2f* __restrict__ tw1, const v2f* __restrict__ tw2,
        const v2f* __restrict__ tw3, h2f* __restrict__ GT){
    __shared__ v2f lds[4096];
    int t = threadIdx.x;
    int cp = blockIdx.x;                  // c' column index
    v2f r[16];
    size_t base = (size_t)cp * 2048;
#pragma unroll
    for (int q = 4; q < 12; ++q)
        r[q] = tof(F1T[base + t + 256*(q-4)]); // y = t + 256 q, nonzero half
    front_fwd<true>(r, t, tw1, tw2, tw3);
    x_strided_to_mid(r, lds, t);
    mid_fwd(r, t & 15, tw1, tw2, tw3);
    x_mid_to_contig(r, lds, t);
    tail_fwd(r);
    // ---- H multiply in digit-reversed frequency domain (incl. 1/N^2) ----
    int pcol = ((cp & 255) << 4) | (cp >> 8);
    int kx = digitrev12(pcol);
    int kxs = (kx + 2048) & 4095;
    float fxv = ((float)(kxs + 1) - 2048.0f) / SENSOR_DF;
    float fx2 = fxv * fxv;
    int rt = __brev((unsigned)t) >> 24;
    rt = ((rt & 0x55) << 1) | ((rt >> 1) & 0x55);   // 4-digit base-4 reversal of t
#pragma unroll
    for (int g = 0; g < 16; ++g){
        const int rg = ((g & 3) << 2) | (g >> 2);
        int ky = rg * 256 + rt;                      // digitrev12(16 t + g)
        int kys = (ky + 2048) & 4095;
        float fyv = ((float)(kys + 1) - 2048.0f) / SENSOR_DF;
        float arg = ILAM2F - fx2 - fyv*fyv;
        arg = fmaxf(arg, 0.0f);
        float w1v = sqrtf(arg);
        float Hp = (TPF * w1v) * D2F;                // exact ref fp32 value
        float v  = Hp * INV_TPF;
        float nn = rintf(v);
        float rr = fmaf(nn, -TPH, Hp);
        rr       = fmaf(nn, -TPL, rr);
        float rev = rr * INV_TPF;                    // in [-0.5, 0.5]
        float sn = __builtin_amdgcn_sinf(rev);
        float cs = __builtin_amdgcn_cosf(rev);
        r[g] = cmul(r[g], mkv(cs * SCALE, sn * SCALE));
    }
    head_inv(r);
    x_contig_to_mid(r, lds, t);
    mid_inv(r, t & 15, tw1, tw2, tw3);
    x_mid_to_strided(r, lds, t);
    v2f o6, o7, o8, o9;
    back_inv_crop(r, t, tw1, tw2, tw3, o6, o7, o8, o9);
    size_t ob = (size_t)cp * 728;
    // crop y in [1685, 2413): idx = t + 256q - 1685
    if (t >= 149) GT[ob + t - 149] = toh(o6);
    GT[ob + t + 107] = toh(o7);
    GT[ob + t + 363] = toh(o8);
    if (t < 109)  GT[ob + t + 619] = toh(o9);
}

// ---------------- pass 3: inv row FFT on crop rows, |.|^2 -------------------
__global__ __launch_bounds__(256, 8) void k_pass3(const h2f* __restrict__ G,
        float* __restrict__ out, float* __restrict__ partials,
        const v2f* __restrict__ tw1, const v2f* __restrict__ tw2,
        const v2f* __restrict__ tw3){
    __shared__ v2f lds[4096];
    int t = threadIdx.x;
    int row = blockIdx.x;
    v2f r[16];
    size_t base = (size_t)row * 4096;
#pragma unroll
    for (int g = 0; g < 16; ++g)
        r[g] = tof(G[base + 256*g + t]);  // c' = 256 g + t <-> p = 16 t + g
    head_inv(r);
    x_contig_to_mid(r, lds, t);
    mid_inv(r, t & 15, tw1, tw2, tw3);
    x_mid_to_strided(r, lds, t);
    v2f o6, o7, o8, o9;
    back_inv_crop(r, t, tw1, tw2, tw3, o6, o7, o8, o9);
    float lsum = 0.0f;
    size_t ob = (size_t)row * 728;
    if (t >= 149){ float I = o6.x*o6.x + o6.y*o6.y; out[ob + t - 149] = I; lsum += I; }
    { float I = o7.x*o7.x + o7.y*o7.y; out[ob + t + 107] = I; lsum += I; }
    { float I = o8.x*o8.x + o8.y*o8.y; out[ob + t + 363] = I; lsum += I; }
    if (t < 109){ float I = o9.x*o9.x + o9.y*o9.y; out[ob + t + 619] = I; lsum += I; }
    __syncthreads();                       // all exchange reads done
    float* red = (float*)lds;
    red[t] = lsum;
    __syncthreads();
    for (int k2 = 128; k2 > 0; k2 >>= 1){
        if (t < k2) red[t] += red[t + k2];
        __syncthreads();
    }
    if (t == 0) partials[row] = red[0];
}

// ---------------- normalize (per-block redundant deterministic reduce) ------
__global__ __launch_bounds__(256) void k_norm(float* __restrict__ out,
                                              const float* __restrict__ partials,
                                              int n){
    __shared__ float red[256];
    int t = threadIdx.x;
    float s = 0.0f;
    for (int i = t; i < 728; i += 256) s += partials[i];
    red[t] = s;
    __syncthreads();
    for (int k = 128; k > 0; k >>= 1){
        if (t < k) red[t] += red[t + k];
        __syncthreads();
    }
    float total = red[0];
    int i = blockIdx.x * 256 + t;
    if (i < n) out[i] = out[i] / total;
}

// ---------------- launch ----------------
extern "C" void kernel_launch(void* const* d_in, const int* in_sizes, int n_in,
                              void* d_out, int out_size, void* d_ws, size_t ws_size,
                              hipStream_t stream) {
    const float* p   = (const float*)d_in[0];
    float*       out = (float*)d_out;
    char*        ws  = (char*)d_ws;

    float* Mv       = (float*)(ws + 8192);         // 2048 f
    float* partials = (float*)(ws + 16384);        // 728 f
    v2f*   tw1      = (v2f*)(ws + 24576);          // 1360 c (fp32)
    v2f*   tw2      = (v2f*)(ws + 40960);
    v2f*   tw3      = (v2f*)(ws + 57344);

    const size_t BIG = (size_t)64 * 1024 * 1024;
    h2f* F1  = (h2f*)(ws + (1 << 20));             // [2048][4096] fp16c, 32MB
    h2f* F1T = (h2f*)(ws + (1 << 20) + BIG);       // [4096][2048] fp16c
    h2f* GT  = F1;                                  // reuse: [4096][728]
    h2f* G   = F1T;                                 // reuse: [728][4096]

    k_setup<<<14, 256, 0, stream>>>(p, Mv, tw1, tw2, tw3);
    k_pass1<<<2048, 256, 0, stream>>>(p, Mv, tw1, tw2, tw3, F1);
    k_transpose_h<<<dim3(128, 64), dim3(16, 16), 0, stream>>>((const unsigned*)F1, (unsigned*)F1T, 2048, 4096);
    k_pass2<<<4096, 256, 0, stream>>>(F1T, tw1, tw2, tw3, GT);
    k_transpose_h<<<dim3(23, 128), dim3(16, 16), 0, stream>>>((const unsigned*)GT, (unsigned*)G, 4096, 728);
    k_pass3<<<728, 256, 0, stream>>>(G, out, partials, tw1, tw2, tw3);
    int n = out_size;
    k_norm<<<(n + 255) / 256, 256, 0, stream>>>(out, partials, n);
}

// Round 15
// 113.957 us; speedup vs baseline: 1.0847x; 1.0037x over previous
//
#include <hip/hip_runtime.h>
#include <math.h>

// ---------------- constants (replicate reference fp32 op order) -------------
constexpr double dPI     = 3.14159265358979323846;
constexpr double dLAMBDA = 5.32e-7;
constexpr double dK      = 2.0 * dPI / dLAMBDA;
constexpr double dD1     = 0.05;
constexpr double dD2     = 0.05;
constexpr double dFOCAL  = dD1 * dD2 / (dD1 + dD2);      // 0.025

constexpr float C1F         = (float)(dK / (2.0 * dD1)); // input_phase coeff
constexpr float KFF         = (float)dK;
constexpr float TWO_FOCAL_F = (float)(2.0 * dFOCAL);     // 0.05
constexpr float TPF         = (float)(2.0 * dPI);
constexpr float INV_TPF     = (float)(1.0 / (2.0 * dPI));
constexpr float TPH         = (float)(2.0 * dPI);                     // 2pi hi
constexpr float TPL         = (float)(2.0 * dPI - (double)TPH);       // 2pi lo
constexpr float SENSOR_DF   = (float)(4096.0 * 2e-6);    // 8.192e-3
constexpr float ILAM2F      = (float)((1.0 / dLAMBDA) * (1.0 / dLAMBDA));
constexpr float D2F         = (float)dD2;
constexpr float PITCHF      = 2e-6f;
constexpr float SCALE       = 1.0f / 16777216.0f;        // 2^-24 = 1/(4096*4096)

// tridiag(1,4,1) inverse kernel constants
constexpr float TRI_R = -0.2679491924311227f;            // -2+sqrt(3)
constexpr float TRI_C = 0.2886751345948129f;             // 1/(2*sqrt(3))

// ---------------- packed complex types ----------------
typedef float    v2f __attribute__((ext_vector_type(2)));
typedef _Float16 h2f __attribute__((ext_vector_type(2)));

__device__ __forceinline__ v2f mkv(float a, float b){ v2f r; r.x=a; r.y=b; return r; }
__device__ __forceinline__ h2f toh(v2f v){ h2f h; h.x=(_Float16)v.x; h.y=(_Float16)v.y; return h; }
__device__ __forceinline__ v2f tof(h2f h){ return mkv((float)h.x, (float)h.y); }

// ---------- packed-FP32 VOP3P primitives (gfx90a+/gfx950) ----------
// complex held as (re=lo, im=hi) in a VGPR pair.
__device__ __forceinline__ v2f pkadd(v2f a, v2f b){
    v2f d;
    asm("v_pk_add_f32 %0, %1, %2" : "=v"(d) : "v"(a), "v"(b));
    return d;
}
__device__ __forceinline__ v2f pksub(v2f a, v2f b){
    v2f d;
    asm("v_pk_add_f32 %0, %1, %2 neg_lo:[0,1] neg_hi:[0,1]" : "=v"(d) : "v"(a), "v"(b));
    return d;
}
// a - i*b = (a.x + b.y, a.y - b.x)
__device__ __forceinline__ v2f addmi(v2f a, v2f b){
    v2f d;
    asm("v_pk_add_f32 %0, %1, %2 op_sel:[0,1] op_sel_hi:[1,0] neg_hi:[0,1]"
        : "=v"(d) : "v"(a), "v"(b));
    return d;
}
// a + i*b = (a.x - b.y, a.y + b.x)
__device__ __forceinline__ v2f addpi(v2f a, v2f b){
    v2f d;
    asm("v_pk_add_f32 %0, %1, %2 op_sel:[0,1] op_sel_hi:[1,0] neg_lo:[0,1]"
        : "=v"(d) : "v"(a), "v"(b));
    return d;
}
// complex multiply: 2 VOP3P ops (AMD canonical pattern)
__device__ __forceinline__ v2f cmul(v2f a, v2f b){
    v2f t, d;
    asm("v_pk_mul_f32 %0, %1, %2 op_sel:[0,0] op_sel_hi:[0,1]"
        : "=v"(t) : "v"(a), "v"(b));
    asm("v_pk_fma_f32 %0, %1, %2, %3 op_sel:[1,1,0] op_sel_hi:[1,0,1] neg_lo:[1,0,0]"
        : "=v"(d) : "v"(a), "v"(b), "v"(t));
    return d;
}
// a * conj(b)
__device__ __forceinline__ v2f cmulc(v2f a, v2f b){
    v2f t, d;
    asm("v_pk_mul_f32 %0, %1, %2 op_sel:[0,0] op_sel_hi:[0,1]"
        : "=v"(t) : "v"(a), "v"(b));
    asm("v_pk_fma_f32 %0, %1, %2, %3 op_sel:[1,1,0] op_sel_hi:[1,0,1] neg_hi:[0,0,1]"
        : "=v"(d) : "v"(a), "v"(b), "v"(t));
    return d;
}

__device__ __forceinline__ int digitrev12(int p){
    int r = __brev((unsigned)p) >> 20;
    return ((r & 0x555) << 1) | ((r >> 1) & 0x555);
}

// ---------------- radix-4 butterflies (DIF fwd / DIT inv) ----------------
__device__ __forceinline__ void bfly_fwd(v2f& A, v2f& B, v2f& C, v2f& D,
                                         v2f w1, v2f w2, v2f w3){
    v2f t0=pkadd(A,C), t1=pksub(A,C), t2=pkadd(B,D), t3=pksub(B,D);
    v2f y0=pkadd(t0,t2);
    v2f y1=addmi(t1,t3);
    v2f y2=pksub(t0,t2);
    v2f y3=addpi(t1,t3);
    A=y0; B=cmul(y1,w1); C=cmul(y2,w2); D=cmul(y3,w3);
}
__device__ __forceinline__ void bfly_fwd_nt(v2f& A, v2f& B, v2f& C, v2f& D){
    v2f t0=pkadd(A,C), t1=pksub(A,C), t2=pkadd(B,D), t3=pksub(B,D);
    A=pkadd(t0,t2);
    v2f y1=addmi(t1,t3);
    v2f y2=pksub(t0,t2);
    v2f y3=addpi(t1,t3);
    B=y1; C=y2; D=y3;
}
__device__ __forceinline__ void bfly_inv(v2f& A, v2f& B, v2f& C, v2f& D,
                                         v2f w1, v2f w2, v2f w3){
    v2f bb=cmulc(B,w1), cc=cmulc(C,w2), dd=cmulc(D,w3);
    v2f t0=pkadd(A,cc), t1=pksub(A,cc), t2=pkadd(bb,dd), t3=pksub(bb,dd);
    A=pkadd(t0,t2);
    B=addpi(t1,t3);
    C=pksub(t0,t2);
    D=addmi(t1,t3);
}
__device__ __forceinline__ void bfly_inv_nt(v2f& A, v2f& B, v2f& C, v2f& D){
    v2f t0=pkadd(A,C), t1=pksub(A,C), t2=pkadd(B,D), t3=pksub(B,D);
    A=pkadd(t0,t2);
    B=addpi(t1,t3);
    C=pksub(t0,t2);
    D=addmi(t1,t3);
}

// ---------------- register-fused stage pairs (table twiddles) ---------------
// ownership A (strided): r[q] = x[t + 256 q]
template<bool ZAD>
__device__ __forceinline__ void front_fwd(v2f* r, int t,
        const v2f* __restrict__ tw1, const v2f* __restrict__ tw2,
        const v2f* __restrict__ tw3){
#pragma unroll
    for (int j = 0; j < 4; ++j){
        int m = t + 256*j;
        v2f w1 = tw1[m], w2 = tw2[m], w3 = tw3[m];
        v2f y0, y1, y2, y3;
        if (ZAD){
            v2f Bv = r[j+4], Cv = r[j+8];          // A = D = 0
            v2f nC = mkv(-Cv.x, -Cv.y);
            y0 = pkadd(Cv, Bv);
            y1 = addmi(nC, Bv);
            y2 = pksub(Cv, Bv);
            y3 = addpi(nC, Bv);
        } else {
            v2f Av=r[j], Bv=r[j+4], Cv=r[j+8], Dv=r[j+12];
            v2f t0=pkadd(Av,Cv), t1=pksub(Av,Cv), t2=pkadd(Bv,Dv), t3=pksub(Bv,Dv);
            y0=pkadd(t0,t2);
            y1=addmi(t1,t3);
            y2=pksub(t0,t2);
            y3=addpi(t1,t3);
        }
        r[j]=y0; r[j+4]=cmul(y1,w1); r[j+8]=cmul(y2,w2); r[j+12]=cmul(y3,w3);
    }
    v2f w1 = tw1[1024+t], w2 = tw2[1024+t], w3 = tw3[1024+t];
#pragma unroll
    for (int k = 0; k < 4; ++k)
        bfly_fwd(r[4*k], r[4*k+1], r[4*k+2], r[4*k+3], w1, w2, w3);
}
// i5 full + i6 pruned to crop outputs (q6..q9)
__device__ __forceinline__ void back_inv_crop(v2f* r, int t,
        const v2f* __restrict__ tw1, const v2f* __restrict__ tw2,
        const v2f* __restrict__ tw3,
        v2f& o6, v2f& o7, v2f& o8, v2f& o9){
    v2f w1 = tw1[1024+t], w2 = tw2[1024+t], w3 = tw3[1024+t];
#pragma unroll
    for (int k = 0; k < 4; ++k)
        bfly_inv(r[4*k], r[4*k+1], r[4*k+2], r[4*k+3], w1, w2, w3);
    {   v2f u1=tw1[t], u2=tw2[t], u3=tw3[t];
        v2f bb=cmulc(r[4],u1), cc=cmulc(r[8],u2), dd=cmulc(r[12],u3);
        o8 = pksub(pkadd(r[0],cc), pkadd(bb,dd));
    }
    {   v2f u1=tw1[t+256], u2=tw2[t+256], u3=tw3[t+256];
        v2f bb=cmulc(r[5],u1), cc=cmulc(r[9],u2), dd=cmulc(r[13],u3);
        o9 = pksub(pkadd(r[1],cc), pkadd(bb,dd));
    }
    {   v2f u1=tw1[t+512], u2=tw2[t+512], u3=tw3[t+512];
        v2f bb=cmulc(r[6],u1), cc=cmulc(r[10],u2), dd=cmulc(r[14],u3);
        v2f t1=pksub(r[2],cc), t3=pksub(bb,dd);
        o6 = addpi(t1,t3);
    }
    {   v2f u1=tw1[t+768], u2=tw2[t+768], u3=tw3[t+768];
        v2f bb=cmulc(r[7],u1), cc=cmulc(r[11],u2), dd=cmulc(r[15],u3);
        v2f t1=pksub(r[3],cc), t3=pksub(bb,dd);
        o7 = addpi(t1,t3);
    }
}
__device__ __forceinline__ void mid_fwd(v2f* r, int c,
        const v2f* __restrict__ tw1, const v2f* __restrict__ tw2,
        const v2f* __restrict__ tw3){
#pragma unroll
    for (int h = 0; h < 4; ++h){
        int idx = 1280 + 16*h + c;
        bfly_fwd(r[h], r[h+4], r[h+8], r[h+12], tw1[idx], tw2[idx], tw3[idx]);
    }
    v2f w1 = tw1[1344+c], w2 = tw2[1344+c], w3 = tw3[1344+c];
#pragma unroll
    for (int j = 0; j < 4; ++j)
        bfly_fwd(r[4*j], r[4*j+1], r[4*j+2], r[4*j+3], w1, w2, w3);
}
__device__ __forceinline__ void mid_inv(v2f* r, int c,
        const v2f* __restrict__ tw1, const v2f* __restrict__ tw2,
        const v2f* __restrict__ tw3){
    v2f w1 = tw1[1344+c], w2 = tw2[1344+c], w3 = tw3[1344+c];
#pragma unroll
    for (int j = 0; j < 4; ++j)
        bfly_inv(r[4*j], r[4*j+1], r[4*j+2], r[4*j+3], w1, w2, w3);
#pragma unroll
    for (int h = 0; h < 4; ++h){
        int idx = 1280 + 16*h + c;
        bfly_inv(r[h], r[h+4], r[h+8], r[h+12], tw1[idx], tw2[idx], tw3[idx]);
    }
}
#define C16F 0.9238795325112867f
#define S16F 0.3826834323650898f
#define C8F  0.7071067811865476f
__device__ __forceinline__ void tail_fwd(v2f* r){
    const v2f W1[4] = {mkv(1,0),mkv(C16F,-S16F),mkv(C8F,-C8F),mkv(S16F,-C16F)};
    const v2f W2[4] = {mkv(1,0),mkv(C8F,-C8F),mkv(0,-1),mkv(-C8F,-C8F)};
    const v2f W3[4] = {mkv(1,0),mkv(S16F,-C16F),mkv(-C8F,-C8F),mkv(-C16F,S16F)};
    bfly_fwd_nt(r[0], r[4], r[8], r[12]);
#pragma unroll
    for (int m = 1; m < 4; ++m)
        bfly_fwd(r[m], r[m+4], r[m+8], r[m+12], W1[m], W2[m], W3[m]);
#pragma unroll
    for (int h = 0; h < 4; ++h)
        bfly_fwd_nt(r[4*h], r[4*h+1], r[4*h+2], r[4*h+3]);
}
__device__ __forceinline__ void head_inv(v2f* r){
    const v2f W1[4] = {mkv(1,0),mkv(C16F,-S16F),mkv(C8F,-C8F),mkv(S16F,-C16F)};
    const v2f W2[4] = {mkv(1,0),mkv(C8F,-C8F),mkv(0,-1),mkv(-C8F,-C8F)};
    const v2f W3[4] = {mkv(1,0),mkv(S16F,-C16F),mkv(-C8F,-C8F),mkv(-C16F,S16F)};
#pragma unroll
    for (int h = 0; h < 4; ++h)
        bfly_inv_nt(r[4*h], r[4*h+1], r[4*h+2], r[4*h+3]);
    bfly_inv_nt(r[0], r[4], r[8], r[12]);
#pragma unroll
    for (int m = 1; m < 4; ++m)
        bfly_inv(r[m], r[m+4], r[m+8], r[m+12], W1[m], W2[m], W3[m]);
}

// ---------------- LDS ownership exchanges (v2f, XOR-swizzled, 1 barrier) ----
__device__ __forceinline__ void x_strided_to_mid(v2f* r, v2f* lds, int t){
    int tsw = t ^ (t >> 4);
#pragma unroll
    for (int q = 0; q < 16; ++q) lds[256*q + tsw] = r[q];
    __syncthreads();
    int Bq = (t >> 4) * 256, c = t & 15;
#pragma unroll
    for (int g = 0; g < 16; ++g) r[g] = lds[Bq + 16*g + (c ^ g)];
}
__device__ __forceinline__ void x_mid_to_contig(v2f* r, v2f* lds, int t){
    int Bq = (t >> 4) * 256, c = t & 15;
#pragma unroll
    for (int g = 0; g < 16; ++g) lds[Bq + 16*g + (c ^ g)] = r[g];
    __syncthreads();
    int tl = t & 15, base = 16*t;
#pragma unroll
    for (int g = 0; g < 16; ++g) r[g] = lds[base + (g ^ tl)];
}
__device__ __forceinline__ void x_contig_to_mid(v2f* r, v2f* lds, int t){
    int tl = t & 15, base = 16*t;
#pragma unroll
    for (int g = 0; g < 16; ++g) lds[base + (g ^ tl)] = r[g];
    __syncthreads();
    int Bq = (t >> 4) * 256, c = t & 15;
#pragma unroll
    for (int g = 0; g < 16; ++g) r[g] = lds[Bq + 16*g + (c ^ g)];
}
__device__ __forceinline__ void x_mid_to_strided(v2f* r, v2f* lds, int t){
    int Bq = (t >> 4) * 256, c = t & 15;
#pragma unroll
    for (int g = 0; g < 16; ++g) lds[Bq + 16*g + (c ^ g)] = r[g];
    __syncthreads();
    int tsw = t ^ (t >> 4);
#pragma unroll
    for (int q = 0; q < 16; ++q) r[q] = lds[256*q + tsw];
}

// ------- setup: spline tridiag solve (blocks 0-7) + twiddles (blocks 8-13) --
// twiddles: fp64-generated (HW-trig version regressed absmax to 1.7e-3, r14)
__global__ __launch_bounds__(256) void k_setup(const float* __restrict__ p,
        float* __restrict__ Mv, v2f* __restrict__ tw1,
        v2f* __restrict__ tw2, v2f* __restrict__ tw3){
    int bid = blockIdx.x;
    int t = threadIdx.x;
    if (bid >= 8){
        int idx = (bid - 8) * 256 + t;
        if (idx >= 1360) return;
        int m, L;
        if (idx < 1024)      { m = idx;        L = 4096; }
        else if (idx < 1280) { m = idx - 1024; L = 1024; }
        else if (idx < 1344) { m = idx - 1280; L = 256;  }
        else                 { m = idx - 1344; L = 64;   }
        double ang = -2.0 * dPI * (double)m / (double)L;
        double s1, c1, s2, c2v, s3, c3;
        sincos(ang, &s1, &c1);
        sincos(2.0*ang, &s2, &c2v);
        sincos(3.0*ang, &s3, &c3);
        tw1[idx] = mkv((float)c1,  (float)s1);
        tw2[idx] = mkv((float)c2v, (float)s2);
        tw3[idx] = mkv((float)c3,  (float)s3);
        return;
    }
    __shared__ float sY[328];
    int B0 = bid * 256;
    for (int k = t; k < 324; k += 256){
        int jg = B0 - 32 + k;                 // Y[j] = j<1024 ? p[j>>1] : 0
        sY[k] = (jg >= 0 && jg < 1024) ? p[jg >> 1] : 0.0f;
    }
    __syncthreads();
    int i = B0 + t;
    if (i >= 2046) return;
    auto rhs = [&](int j) -> float {
        if (j < 0 || j >= 2046) return 0.0f;
        int l = j - B0 + 32;
        return 6.0f * (sY[l+2] - 2.0f*sY[l+1] + sY[l]);
    };
    float x = TRI_C * rhs(i);
    float wd = TRI_C;
    for (int d = 1; d <= 32; ++d){
        wd *= TRI_R;
        x += wd * (rhs(i-d) + rhs(i+d));
    }
    if (i < 48){
        float cA = 0.0f, wj = TRI_C;
        for (int j = 0; j < 32; ++j){ wj *= TRI_R; cA += wj * rhs(j); }
        float rp = 1.0f;
        for (int k = 0; k <= i; ++k) rp *= TRI_R;
        x -= cA * rp;
    }
    if (i >= 1998){
        float cB = 0.0f, wj = TRI_C;
        for (int j = 0; j < 32; ++j){ wj *= TRI_R; cB += wj * rhs(2045 - j); }
        float rp = 1.0f;
        for (int k = 0; k < 2046 - i; ++k) rp *= TRI_R;
        x -= cB * rp;
    }
    Mv[i+1] = x;
    if (i == 0)    Mv[0]    = 0.0f;
    if (i == 2045) Mv[2047] = 0.0f;
}

// ---------------- pass 1: field build + fwd row FFT (fp16 out) --------------
__global__ __launch_bounds__(256) void k_pass1(const float* __restrict__ p,
        const float* __restrict__ Mv,
        const v2f* __restrict__ tw1, const v2f* __restrict__ tw2,
        const v2f* __restrict__ tw3, h2f* __restrict__ F1){
    __shared__ v2f lds[4096];
    float* ldsf = (float*)lds;
    int t = threadIdx.x;
    int row = blockIdx.x;                 // y = 1024 + row
    v2f r[16];
    // stage spline tables in LDS (buffer free until first exchange)
    for (int j = t; j < 512; j += 256)  ldsf[j] = p[j];
    for (int j = t; j < 2048; j += 256) ldsf[512 + j] = Mv[j];
    __syncthreads();
    int y = 1024 + row;
    int iy = row;
    int a = (iy < 1024) ? (1023 - iy) : (iy - 1024);
    float fy = PITCHF * (float)(y - 2048);
    float cy2 = fy * fy;
    float af = (float)a + 0.5f;
#pragma unroll
    for (int q = 4; q < 12; ++q){
        int x = t + 256*q;                // in [1024, 3072)
        int ix = x - 1024;
        int b = (ix < 1024) ? (1023 - ix) : (ix - 1024);
        float bf = (float)b + 0.5f;
        float rq = sqrtf(af*af + bf*bf);
        int ind = (int)rq; if (ind > 2046) ind = 2046;
        float tt = rq - (float)ind;
        float y0v = (ind < 1024) ? ldsf[ind >> 1] : 0.0f;        // Y[ind]
        float y1v = (ind + 1 < 1024) ? ldsf[(ind + 1) >> 1] : 0.0f; // Y[ind+1]
        float m0 = ldsf[512 + ind], m1 = ldsf[512 + ind + 1];
        float bb = (y1v - y0v) - (2.0f*m0 + m1) / 6.0f;
        float bias = y0v + tt*(bb + tt*(m0/2.0f + tt*(m1-m0)/6.0f));
        float fx = PITCHF * (float)(x - 2048);
        float r2 = fx*fx + cy2;
        float ip = C1F * r2;
        float lp = -((KFF * r2) / TWO_FOCAL_F);
        float sp = ip + lp + bias;
        float fv = sp * INV_TPF;                     // phase in revolutions
        float fr = fv - floorf(fv);                  // [0,1)
        float sn = __builtin_amdgcn_sinf(fr);
        float cs = __builtin_amdgcn_cosf(fr);
        r[q] = mkv(cs, sn);
    }
    __syncthreads();                      // staged-table reads done
    front_fwd<true>(r, t, tw1, tw2, tw3);
    x_strided_to_mid(r, lds, t);
    mid_fwd(r, t & 15, tw1, tw2, tw3);
    x_mid_to_contig(r, lds, t);
    tail_fwd(r);
    size_t base = (size_t)row * 4096;
#pragma unroll
    for (int g = 0; g < 16; ++g)
        F1[base + 256*g + t] = toh(r[g]);  // coalesced per g
}

// ------- tiled 4-byte transpose, uint4-vectorized 64x64 tiles ---------------
__global__ __launch_bounds__(256) void k_transpose_h(const unsigned* __restrict__ in,
                                                     unsigned* __restrict__ out,
                                                     int H, int W){
    __shared__ unsigned tile[64][65];
    int bx = blockIdx.x * 64, by = blockIdx.y * 64;  // bx: W dim, by: H dim
    int tx = threadIdx.x, ty = threadIdx.y;   // (16,16)
#pragma unroll
    for (int k = 0; k < 4; ++k){
        int rr = by + ty + 16*k;          // H always multiple of 64
        int cc = bx + 4*tx;
        if (cc + 3 < W){
            uint4 v = *(const uint4*)&in[(size_t)rr * W + cc];
            tile[ty+16*k][4*tx+0] = v.x;
            tile[ty+16*k][4*tx+1] = v.y;
            tile[ty+16*k][4*tx+2] = v.z;
            tile[ty+16*k][4*tx+3] = v.w;
        } else {
#pragma unroll
            for (int j = 0; j < 4; ++j)
                if (cc + j < W) tile[ty+16*k][4*tx+j] = in[(size_t)rr * W + cc + j];
        }
    }
    __syncthreads();
#pragma unroll
    for (int k = 0; k < 4; ++k){
        int rr = bx + ty + 16*k;
        int cc = by + 4*tx;               // always < H
        if (rr < W){
            uint4 v;
            v.x = tile[4*tx+0][ty+16*k];
            v.y = tile[4*tx+1][ty+16*k];
            v.z = tile[4*tx+2][ty+16*k];
            v.w = tile[4*tx+3][ty+16*k];
            *(uint4*)&out[(size_t)rr * H + cc] = v;
        }
    }
}

// ---------------- pass 2: col fwd FFT + H + col inv FFT, crop ---------------
__global__ __launch_bounds__(256, 8) void k_pass2(const h2f* __restrict__ F1T,
        const v2f* __restrict__ tw1, const v2f* __restrict__ tw2,
        const v2f* __restrict__ tw3, h2f* __restrict__ GT){
    __shared__ v2f lds[4096];
    int t = threadIdx.x;
    int cp = blockIdx.x;                  // c' column index
    v2f r[16];
    size_t base = (size_t)cp * 2048;
#pragma unroll
    for (int q = 4; q < 12; ++q)
        r[q] = tof(F1T[base + t + 256*(q-4)]); // y = t + 256 q, nonzero half
    front_fwd<true>(r, t, tw1, tw2, tw3);
    x_strided_to_mid(r, lds, t);
    mid_fwd(r, t & 15, tw1, tw2, tw3);
    x_mid_to_contig(r, lds, t);
    tail_fwd(r);
    // ---- H multiply in digit-reversed frequency domain (incl. 1/N^2) ----
    int pcol = ((cp & 255) << 4) | (cp >> 8);
    int kx = digitrev12(pcol);
    int kxs = (kx + 2048) & 4095;
    float fxv = ((float)(kxs + 1) - 2048.0f) / SENSOR_DF;
    float fx2 = fxv * fxv;
    int rt = __brev((unsigned)t) >> 24;
    rt = ((rt & 0x55) << 1) | ((rt >> 1) & 0x55);   // 4-digit base-4 reversal of t
#pragma unroll
    for (int g = 0; g < 16; ++g){
        const int rg = ((g & 3) << 2) | (g >> 2);
        int ky = rg * 256 + rt;                      // digitrev12(16 t + g)
        int kys = (ky + 2048) & 4095;
        float fyv = ((float)(kys + 1) - 2048.0f) / SENSOR_DF;
        float arg = ILAM2F - fx2 - fyv*fyv;
        arg = fmaxf(arg, 0.0f);
        float w1v = sqrtf(arg);
        float Hp = (TPF * w1v) * D2F;                // exact ref fp32 value
        float v  = Hp * INV_TPF;
        float nn = rintf(v);
        float rr = fmaf(nn, -TPH, Hp);
        rr       = fmaf(nn, -TPL, rr);
        float rev = rr * INV_TPF;                    // in [-0.5, 0.5]
        float sn = __builtin_amdgcn_sinf(rev);
        float cs = __builtin_amdgcn_cosf(rev);
        r[g] = cmul(r[g], mkv(cs * SCALE, sn * SCALE));
    }
    head_inv(r);
    x_contig_to_mid(r, lds, t);
    mid_inv(r, t & 15, tw1, tw2, tw3);
    x_mid_to_strided(r, lds, t);
    v2f o6, o7, o8, o9;
    back_inv_crop(r, t, tw1, tw2, tw3, o6, o7, o8, o9);
    size_t ob = (size_t)cp * 728;
    // crop y in [1685, 2413): idx = t + 256q - 1685
    if (t >= 149) GT[ob + t - 149] = toh(o6);
    GT[ob + t + 107] = toh(o7);
    GT[ob + t + 363] = toh(o8);
    if (t < 109)  GT[ob + t + 619] = toh(o9);
}

// ---------------- pass 3: inv row FFT on crop rows, |.|^2 -------------------
__global__ __launch_bounds__(256, 8) void k_pass3(const h2f* __restrict__ G,
        float* __restrict__ out, float* __restrict__ partials,
        const v2f* __restrict__ tw1, const v2f* __restrict__ tw2,
        const v2f* __restrict__ tw3){
    __shared__ v2f lds[4096];
    int t = threadIdx.x;
    int row = blockIdx.x;
    v2f r[16];
    size_t base = (size_t)row * 4096;
#pragma unroll
    for (int g = 0; g < 16; ++g)
        r[g] = tof(G[base + 256*g + t]);  // c' = 256 g + t <-> p = 16 t + g
    head_inv(r);
    x_contig_to_mid(r, lds, t);
    mid_inv(r, t & 15, tw1, tw2, tw3);
    x_mid_to_strided(r, lds, t);
    v2f o6, o7, o8, o9;
    back_inv_crop(r, t, tw1, tw2, tw3, o6, o7, o8, o9);
    float lsum = 0.0f;
    size_t ob = (size_t)row * 728;
    if (t >= 149){ float I = o6.x*o6.x + o6.y*o6.y; out[ob + t - 149] = I; lsum += I; }
    { float I = o7.x*o7.x + o7.y*o7.y; out[ob + t + 107] = I; lsum += I; }
    { float I = o8.x*o8.x + o8.y*o8.y; out[ob + t + 363] = I; lsum += I; }
    if (t < 109){ float I = o9.x*o9.x + o9.y*o9.y; out[ob + t + 619] = I; lsum += I; }
    __syncthreads();                       // all exchange reads done
    float* red = (float*)lds;
    red[t] = lsum;
    __syncthreads();
    for (int k2 = 128; k2 > 0; k2 >>= 1){
        if (t < k2) red[t] += red[t + k2];
        __syncthreads();
    }
    if (t == 0) partials[row] = red[0];
}

// ---------------- normalize (per-block redundant deterministic reduce) ------
__global__ __launch_bounds__(256) void k_norm(float* __restrict__ out,
                                              const float* __restrict__ partials,
                                              int n){
    __shared__ float red[256];
    int t = threadIdx.x;
    float s = 0.0f;
    for (int i = t; i < 728; i += 256) s += partials[i];
    red[t] = s;
    __syncthreads();
    for (int k = 128; k > 0; k >>= 1){
        if (t < k) red[t] += red[t + k];
        __syncthreads();
    }
    float total = red[0];
    int i = blockIdx.x * 256 + t;
    if (i < n) out[i] = out[i] / total;
}

// ---------------- launch ----------------
extern "C" void kernel_launch(void* const* d_in, const int* in_sizes, int n_in,
                              void* d_out, int out_size, void* d_ws, size_t ws_size,
                              hipStream_t stream) {
    const float* p   = (const float*)d_in[0];
    float*       out = (float*)d_out;
    char*        ws  = (char*)d_ws;

    float* Mv       = (float*)(ws + 8192);         // 2048 f
    float* partials = (float*)(ws + 16384);        // 728 f
    v2f*   tw1      = (v2f*)(ws + 24576);          // 1360 c (fp32)
    v2f*   tw2      = (v2f*)(ws + 40960);
    v2f*   tw3      = (v2f*)(ws + 57344);

    const size_t BIG = (size_t)64 * 1024 * 1024;
    h2f* F1  = (h2f*)(ws + (1 << 20));             // [2048][4096] fp16c, 32MB
    h2f* F1T = (h2f*)(ws + (1 << 20) + BIG);       // [4096][2048] fp16c
    h2f* GT  = F1;                                  // reuse: [4096][728]
    h2f* G   = F1T;                                 // reuse: [728][4096]

    k_setup<<<14, 256, 0, stream>>>(p, Mv, tw1, tw2, tw3);
    k_pass1<<<2048, 256, 0, stream>>>(p, Mv, tw1, tw2, tw3, F1);
    k_transpose_h<<<dim3(64, 32), dim3(16, 16), 0, stream>>>((const unsigned*)F1, (unsigned*)F1T, 2048, 4096);
    k_pass2<<<4096, 256, 0, stream>>>(F1T, tw1, tw2, tw3, GT);
    k_transpose_h<<<dim3(12, 64), dim3(16, 16), 0, stream>>>((const unsigned*)GT, (unsigned*)G, 4096, 728);
    k_pass3<<<728, 256, 0, stream>>>(G, out, partials, tw1, tw2, tw3);
    int n = out_size;
    k_norm<<<(n + 255) / 256, 256, 0, stream>>>(out, partials, n);
}

// Round 16
// 110.707 us; speedup vs baseline: 1.1165x; 1.0294x over previous
//
#include <hip/hip_runtime.h>
#include <math.h>

// ---------------- constants (replicate reference fp32 op order) -------------
constexpr double dPI     = 3.14159265358979323846;
constexpr double dLAMBDA = 5.32e-7;
constexpr double dK      = 2.0 * dPI / dLAMBDA;
constexpr double dD1     = 0.05;
constexpr double dD2     = 0.05;
constexpr double dFOCAL  = dD1 * dD2 / (dD1 + dD2);      // 0.025

constexpr float C1F         = (float)(dK / (2.0 * dD1)); // input_phase coeff
constexpr float KFF         = (float)dK;
constexpr float TWO_FOCAL_F = (float)(2.0 * dFOCAL);     // 0.05
constexpr float TPF         = (float)(2.0 * dPI);
constexpr float INV_TPF     = (float)(1.0 / (2.0 * dPI));
constexpr float TPH         = (float)(2.0 * dPI);                     // 2pi hi
constexpr float TPL         = (float)(2.0 * dPI - (double)TPH);       // 2pi lo
constexpr float SENSOR_DF   = (float)(4096.0 * 2e-6);    // 8.192e-3
constexpr float ILAM2F      = (float)((1.0 / dLAMBDA) * (1.0 / dLAMBDA));
constexpr float D2F         = (float)dD2;
constexpr float PITCHF      = 2e-6f;
constexpr float SCALE       = 1.0f / 16777216.0f;        // 2^-24 = 1/(4096*4096)

// tridiag(1,4,1) inverse kernel constants
constexpr float TRI_R = -0.2679491924311227f;            // -2+sqrt(3)
constexpr float TRI_C = 0.2886751345948129f;             // 1/(2*sqrt(3))

// ---------------- packed complex types ----------------
typedef float    v2f __attribute__((ext_vector_type(2)));
typedef _Float16 h2f __attribute__((ext_vector_type(2)));

__device__ __forceinline__ v2f mkv(float a, float b){ v2f r; r.x=a; r.y=b; return r; }
__device__ __forceinline__ h2f toh(v2f v){ h2f h; h.x=(_Float16)v.x; h.y=(_Float16)v.y; return h; }
__device__ __forceinline__ v2f tof(h2f h){ return mkv((float)h.x, (float)h.y); }

// ---------- packed-FP32 VOP3P primitives (gfx90a+/gfx950) ----------
__device__ __forceinline__ v2f pkadd(v2f a, v2f b){
    v2f d;
    asm("v_pk_add_f32 %0, %1, %2" : "=v"(d) : "v"(a), "v"(b));
    return d;
}
__device__ __forceinline__ v2f pksub(v2f a, v2f b){
    v2f d;
    asm("v_pk_add_f32 %0, %1, %2 neg_lo:[0,1] neg_hi:[0,1]" : "=v"(d) : "v"(a), "v"(b));
    return d;
}
// a - i*b = (a.x + b.y, a.y - b.x)
__device__ __forceinline__ v2f addmi(v2f a, v2f b){
    v2f d;
    asm("v_pk_add_f32 %0, %1, %2 op_sel:[0,1] op_sel_hi:[1,0] neg_hi:[0,1]"
        : "=v"(d) : "v"(a), "v"(b));
    return d;
}
// a + i*b = (a.x - b.y, a.y + b.x)
__device__ __forceinline__ v2f addpi(v2f a, v2f b){
    v2f d;
    asm("v_pk_add_f32 %0, %1, %2 op_sel:[0,1] op_sel_hi:[1,0] neg_lo:[0,1]"
        : "=v"(d) : "v"(a), "v"(b));
    return d;
}
// complex multiply: 2 VOP3P ops
__device__ __forceinline__ v2f cmul(v2f a, v2f b){
    v2f t, d;
    asm("v_pk_mul_f32 %0, %1, %2 op_sel:[0,0] op_sel_hi:[0,1]"
        : "=v"(t) : "v"(a), "v"(b));
    asm("v_pk_fma_f32 %0, %1, %2, %3 op_sel:[1,1,0] op_sel_hi:[1,0,1] neg_lo:[1,0,0]"
        : "=v"(d) : "v"(a), "v"(b), "v"(t));
    return d;
}
// a * conj(b)
__device__ __forceinline__ v2f cmulc(v2f a, v2f b){
    v2f t, d;
    asm("v_pk_mul_f32 %0, %1, %2 op_sel:[0,0] op_sel_hi:[0,1]"
        : "=v"(t) : "v"(a), "v"(b));
    asm("v_pk_fma_f32 %0, %1, %2, %3 op_sel:[1,1,0] op_sel_hi:[1,0,1] neg_hi:[0,0,1]"
        : "=v"(d) : "v"(a), "v"(b), "v"(t));
    return d;
}

__device__ __forceinline__ int digitrev12(int p){
    int r = __brev((unsigned)p) >> 20;
    return ((r & 0x555) << 1) | ((r >> 1) & 0x555);
}

// ---------------- radix-4 butterflies (DIF fwd / DIT inv) ----------------
__device__ __forceinline__ void bfly_fwd(v2f& A, v2f& B, v2f& C, v2f& D,
                                         v2f w1, v2f w2, v2f w3){
    v2f t0=pkadd(A,C), t1=pksub(A,C), t2=pkadd(B,D), t3=pksub(B,D);
    v2f y0=pkadd(t0,t2);
    v2f y1=addmi(t1,t3);
    v2f y2=pksub(t0,t2);
    v2f y3=addpi(t1,t3);
    A=y0; B=cmul(y1,w1); C=cmul(y2,w2); D=cmul(y3,w3);
}
__device__ __forceinline__ void bfly_fwd_nt(v2f& A, v2f& B, v2f& C, v2f& D){
    v2f t0=pkadd(A,C), t1=pksub(A,C), t2=pkadd(B,D), t3=pksub(B,D);
    A=pkadd(t0,t2);
    v2f y1=addmi(t1,t3);
    v2f y2=pksub(t0,t2);
    v2f y3=addpi(t1,t3);
    B=y1; C=y2; D=y3;
}
__device__ __forceinline__ void bfly_inv(v2f& A, v2f& B, v2f& C, v2f& D,
                                         v2f w1, v2f w2, v2f w3){
    v2f bb=cmulc(B,w1), cc=cmulc(C,w2), dd=cmulc(D,w3);
    v2f t0=pkadd(A,cc), t1=pksub(A,cc), t2=pkadd(bb,dd), t3=pksub(bb,dd);
    A=pkadd(t0,t2);
    B=addpi(t1,t3);
    C=pksub(t0,t2);
    D=addmi(t1,t3);
}
__device__ __forceinline__ void bfly_inv_nt(v2f& A, v2f& B, v2f& C, v2f& D){
    v2f t0=pkadd(A,C), t1=pksub(A,C), t2=pkadd(B,D), t3=pksub(B,D);
    A=pkadd(t0,t2);
    B=addpi(t1,t3);
    C=pksub(t0,t2);
    D=addmi(t1,t3);
}

// ---------------- single-set stage pairs (pass1/pass3) ----------------------
template<bool ZAD>
__device__ __forceinline__ void front_fwd(v2f* r, int t,
        const v2f* __restrict__ tw1, const v2f* __restrict__ tw2,
        const v2f* __restrict__ tw3){
#pragma unroll
    for (int j = 0; j < 4; ++j){
        int m = t + 256*j;
        v2f w1 = tw1[m], w2 = tw2[m], w3 = tw3[m];
        v2f y0, y1, y2, y3;
        if (ZAD){
            v2f Bv = r[j+4], Cv = r[j+8];          // A = D = 0
            v2f nC = mkv(-Cv.x, -Cv.y);
            y0 = pkadd(Cv, Bv);
            y1 = addmi(nC, Bv);
            y2 = pksub(Cv, Bv);
            y3 = addpi(nC, Bv);
        } else {
            v2f Av=r[j], Bv=r[j+4], Cv=r[j+8], Dv=r[j+12];
            v2f t0=pkadd(Av,Cv), t1=pksub(Av,Cv), t2=pkadd(Bv,Dv), t3=pksub(Bv,Dv);
            y0=pkadd(t0,t2);
            y1=addmi(t1,t3);
            y2=pksub(t0,t2);
            y3=addpi(t1,t3);
        }
        r[j]=y0; r[j+4]=cmul(y1,w1); r[j+8]=cmul(y2,w2); r[j+12]=cmul(y3,w3);
    }
    v2f w1 = tw1[1024+t], w2 = tw2[1024+t], w3 = tw3[1024+t];
#pragma unroll
    for (int k = 0; k < 4; ++k)
        bfly_fwd(r[4*k], r[4*k+1], r[4*k+2], r[4*k+3], w1, w2, w3);
}
__device__ __forceinline__ void back_inv_crop(v2f* r, int t,
        const v2f* __restrict__ tw1, const v2f* __restrict__ tw2,
        const v2f* __restrict__ tw3,
        v2f& o6, v2f& o7, v2f& o8, v2f& o9){
    v2f w1 = tw1[1024+t], w2 = tw2[1024+t], w3 = tw3[1024+t];
#pragma unroll
    for (int k = 0; k < 4; ++k)
        bfly_inv(r[4*k], r[4*k+1], r[4*k+2], r[4*k+3], w1, w2, w3);
    {   v2f u1=tw1[t], u2=tw2[t], u3=tw3[t];
        v2f bb=cmulc(r[4],u1), cc=cmulc(r[8],u2), dd=cmulc(r[12],u3);
        o8 = pksub(pkadd(r[0],cc), pkadd(bb,dd));
    }
    {   v2f u1=tw1[t+256], u2=tw2[t+256], u3=tw3[t+256];
        v2f bb=cmulc(r[5],u1), cc=cmulc(r[9],u2), dd=cmulc(r[13],u3);
        o9 = pksub(pkadd(r[1],cc), pkadd(bb,dd));
    }
    {   v2f u1=tw1[t+512], u2=tw2[t+512], u3=tw3[t+512];
        v2f bb=cmulc(r[6],u1), cc=cmulc(r[10],u2), dd=cmulc(r[14],u3);
        v2f t1=pksub(r[2],cc), t3=pksub(bb,dd);
        o6 = addpi(t1,t3);
    }
    {   v2f u1=tw1[t+768], u2=tw2[t+768], u3=tw3[t+768];
        v2f bb=cmulc(r[7],u1), cc=cmulc(r[11],u2), dd=cmulc(r[15],u3);
        v2f t1=pksub(r[3],cc), t3=pksub(bb,dd);
        o7 = addpi(t1,t3);
    }
}
__device__ __forceinline__ void mid_fwd(v2f* r, int c,
        const v2f* __restrict__ tw1, const v2f* __restrict__ tw2,
        const v2f* __restrict__ tw3){
#pragma unroll
    for (int h = 0; h < 4; ++h){
        int idx = 1280 + 16*h + c;
        bfly_fwd(r[h], r[h+4], r[h+8], r[h+12], tw1[idx], tw2[idx], tw3[idx]);
    }
    v2f w1 = tw1[1344+c], w2 = tw2[1344+c], w3 = tw3[1344+c];
#pragma unroll
    for (int j = 0; j < 4; ++j)
        bfly_fwd(r[4*j], r[4*j+1], r[4*j+2], r[4*j+3], w1, w2, w3);
}
__device__ __forceinline__ void mid_inv(v2f* r, int c,
        const v2f* __restrict__ tw1, const v2f* __restrict__ tw2,
        const v2f* __restrict__ tw3){
    v2f w1 = tw1[1344+c], w2 = tw2[1344+c], w3 = tw3[1344+c];
#pragma unroll
    for (int j = 0; j < 4; ++j)
        bfly_inv(r[4*j], r[4*j+1], r[4*j+2], r[4*j+3], w1, w2, w3);
#pragma unroll
    for (int h = 0; h < 4; ++h){
        int idx = 1280 + 16*h + c;
        bfly_inv(r[h], r[h+4], r[h+8], r[h+12], tw1[idx], tw2[idx], tw3[idx]);
    }
}
#define C16F 0.9238795325112867f
#define S16F 0.3826834323650898f
#define C8F  0.7071067811865476f
__device__ __forceinline__ void tail_fwd(v2f* r){
    const v2f W1[4] = {mkv(1,0),mkv(C16F,-S16F),mkv(C8F,-C8F),mkv(S16F,-C16F)};
    const v2f W2[4] = {mkv(1,0),mkv(C8F,-C8F),mkv(0,-1),mkv(-C8F,-C8F)};
    const v2f W3[4] = {mkv(1,0),mkv(S16F,-C16F),mkv(-C8F,-C8F),mkv(-C16F,S16F)};
    bfly_fwd_nt(r[0], r[4], r[8], r[12]);
#pragma unroll
    for (int m = 1; m < 4; ++m)
        bfly_fwd(r[m], r[m+4], r[m+8], r[m+12], W1[m], W2[m], W3[m]);
#pragma unroll
    for (int h = 0; h < 4; ++h)
        bfly_fwd_nt(r[4*h], r[4*h+1], r[4*h+2], r[4*h+3]);
}
__device__ __forceinline__ void head_inv(v2f* r){
    const v2f W1[4] = {mkv(1,0),mkv(C16F,-S16F),mkv(C8F,-C8F),mkv(S16F,-C16F)};
    const v2f W2[4] = {mkv(1,0),mkv(C8F,-C8F),mkv(0,-1),mkv(-C8F,-C8F)};
    const v2f W3[4] = {mkv(1,0),mkv(S16F,-C16F),mkv(-C8F,-C8F),mkv(-C16F,S16F)};
#pragma unroll
    for (int h = 0; h < 4; ++h)
        bfly_inv_nt(r[4*h], r[4*h+1], r[4*h+2], r[4*h+3]);
    bfly_inv_nt(r[0], r[4], r[8], r[12]);
#pragma unroll
    for (int m = 1; m < 4; ++m)
        bfly_inv(r[m], r[m+4], r[m+8], r[m+12], W1[m], W2[m], W3[m]);
}

// ---------------- dual-set stage pairs (pass2, shared twiddle loads) --------
template<bool ZAD>
__device__ __forceinline__ void front_fwd2(v2f* ra, v2f* rb, int t,
        const v2f* __restrict__ tw1, const v2f* __restrict__ tw2,
        const v2f* __restrict__ tw3){
#pragma unroll
    for (int j = 0; j < 4; ++j){
        int m = t + 256*j;
        v2f w1 = tw1[m], w2 = tw2[m], w3 = tw3[m];
#pragma unroll
        for (int s = 0; s < 2; ++s){
            v2f* r = s ? rb : ra;
            v2f y0, y1, y2, y3;
            if (ZAD){
                v2f Bv = r[j+4], Cv = r[j+8];
                v2f nC = mkv(-Cv.x, -Cv.y);
                y0 = pkadd(Cv, Bv);
                y1 = addmi(nC, Bv);
                y2 = pksub(Cv, Bv);
                y3 = addpi(nC, Bv);
            } else {
                v2f Av=r[j], Bv=r[j+4], Cv=r[j+8], Dv=r[j+12];
                v2f t0=pkadd(Av,Cv), t1=pksub(Av,Cv), t2=pkadd(Bv,Dv), t3=pksub(Bv,Dv);
                y0=pkadd(t0,t2);
                y1=addmi(t1,t3);
                y2=pksub(t0,t2);
                y3=addpi(t1,t3);
            }
            r[j]=y0; r[j+4]=cmul(y1,w1); r[j+8]=cmul(y2,w2); r[j+12]=cmul(y3,w3);
        }
    }
    v2f w1 = tw1[1024+t], w2 = tw2[1024+t], w3 = tw3[1024+t];
#pragma unroll
    for (int k = 0; k < 4; ++k){
        bfly_fwd(ra[4*k], ra[4*k+1], ra[4*k+2], ra[4*k+3], w1, w2, w3);
        bfly_fwd(rb[4*k], rb[4*k+1], rb[4*k+2], rb[4*k+3], w1, w2, w3);
    }
}
__device__ __forceinline__ void mid_fwd2(v2f* ra, v2f* rb, int c,
        const v2f* __restrict__ tw1, const v2f* __restrict__ tw2,
        const v2f* __restrict__ tw3){
#pragma unroll
    for (int h = 0; h < 4; ++h){
        int idx = 1280 + 16*h + c;
        v2f u1=tw1[idx], u2=tw2[idx], u3=tw3[idx];
        bfly_fwd(ra[h], ra[h+4], ra[h+8], ra[h+12], u1, u2, u3);
        bfly_fwd(rb[h], rb[h+4], rb[h+8], rb[h+12], u1, u2, u3);
    }
    v2f w1 = tw1[1344+c], w2 = tw2[1344+c], w3 = tw3[1344+c];
#pragma unroll
    for (int j = 0; j < 4; ++j){
        bfly_fwd(ra[4*j], ra[4*j+1], ra[4*j+2], ra[4*j+3], w1, w2, w3);
        bfly_fwd(rb[4*j], rb[4*j+1], rb[4*j+2], rb[4*j+3], w1, w2, w3);
    }
}
__device__ __forceinline__ void mid_inv2(v2f* ra, v2f* rb, int c,
        const v2f* __restrict__ tw1, const v2f* __restrict__ tw2,
        const v2f* __restrict__ tw3){
    v2f w1 = tw1[1344+c], w2 = tw2[1344+c], w3 = tw3[1344+c];
#pragma unroll
    for (int j = 0; j < 4; ++j){
        bfly_inv(ra[4*j], ra[4*j+1], ra[4*j+2], ra[4*j+3], w1, w2, w3);
        bfly_inv(rb[4*j], rb[4*j+1], rb[4*j+2], rb[4*j+3], w1, w2, w3);
    }
#pragma unroll
    for (int h = 0; h < 4; ++h){
        int idx = 1280 + 16*h + c;
        v2f u1=tw1[idx], u2=tw2[idx], u3=tw3[idx];
        bfly_inv(ra[h], ra[h+4], ra[h+8], ra[h+12], u1, u2, u3);
        bfly_inv(rb[h], rb[h+4], rb[h+8], rb[h+12], u1, u2, u3);
    }
}
__device__ __forceinline__ void back_inv_crop2(v2f* ra, v2f* rb, int t,
        const v2f* __restrict__ tw1, const v2f* __restrict__ tw2,
        const v2f* __restrict__ tw3, v2f* oa, v2f* ob){
    v2f w1 = tw1[1024+t], w2 = tw2[1024+t], w3 = tw3[1024+t];
#pragma unroll
    for (int k = 0; k < 4; ++k){
        bfly_inv(ra[4*k], ra[4*k+1], ra[4*k+2], ra[4*k+3], w1, w2, w3);
        bfly_inv(rb[4*k], rb[4*k+1], rb[4*k+2], rb[4*k+3], w1, w2, w3);
    }
    {   v2f u1=tw1[t], u2=tw2[t], u3=tw3[t];
        v2f bb=cmulc(ra[4],u1), cc=cmulc(ra[8],u2), dd=cmulc(ra[12],u3);
        oa[2] = pksub(pkadd(ra[0],cc), pkadd(bb,dd));
        bb=cmulc(rb[4],u1); cc=cmulc(rb[8],u2); dd=cmulc(rb[12],u3);
        ob[2] = pksub(pkadd(rb[0],cc), pkadd(bb,dd));
    }
    {   v2f u1=tw1[t+256], u2=tw2[t+256], u3=tw3[t+256];
        v2f bb=cmulc(ra[5],u1), cc=cmulc(ra[9],u2), dd=cmulc(ra[13],u3);
        oa[3] = pksub(pkadd(ra[1],cc), pkadd(bb,dd));
        bb=cmulc(rb[5],u1); cc=cmulc(rb[9],u2); dd=cmulc(rb[13],u3);
        ob[3] = pksub(pkadd(rb[1],cc), pkadd(bb,dd));
    }
    {   v2f u1=tw1[t+512], u2=tw2[t+512], u3=tw3[t+512];
        v2f bb=cmulc(ra[6],u1), cc=cmulc(ra[10],u2), dd=cmulc(ra[14],u3);
        v2f t1=pksub(ra[2],cc), t3=pksub(bb,dd);
        oa[0] = addpi(t1,t3);
        bb=cmulc(rb[6],u1); cc=cmulc(rb[10],u2); dd=cmulc(rb[14],u3);
        t1=pksub(rb[2],cc); t3=pksub(bb,dd);
        ob[0] = addpi(t1,t3);
    }
    {   v2f u1=tw1[t+768], u2=tw2[t+768], u3=tw3[t+768];
        v2f bb=cmulc(ra[7],u1), cc=cmulc(ra[11],u2), dd=cmulc(ra[15],u3);
        v2f t1=pksub(ra[3],cc), t3=pksub(bb,dd);
        oa[1] = addpi(t1,t3);
        bb=cmulc(rb[7],u1); cc=cmulc(rb[11],u2); dd=cmulc(rb[15],u3);
        t1=pksub(rb[3],cc); t3=pksub(bb,dd);
        ob[1] = addpi(t1,t3);
    }
}

// ---------------- LDS ownership exchanges ----------------
// single-chain (pass1/pass3): 1 barrier each
__device__ __forceinline__ void x_strided_to_mid(v2f* r, v2f* lds, int t){
    int tsw = t ^ (t >> 4);
#pragma unroll
    for (int q = 0; q < 16; ++q) lds[256*q + tsw] = r[q];
    __syncthreads();
    int Bq = (t >> 4) * 256, c = t & 15;
#pragma unroll
    for (int g = 0; g < 16; ++g) r[g] = lds[Bq + 16*g + (c ^ g)];
}
__device__ __forceinline__ void x_mid_to_contig(v2f* r, v2f* lds, int t){
    int Bq = (t >> 4) * 256, c = t & 15;
#pragma unroll
    for (int g = 0; g < 16; ++g) lds[Bq + 16*g + (c ^ g)] = r[g];
    __syncthreads();
    int tl = t & 15, base = 16*t;
#pragma unroll
    for (int g = 0; g < 16; ++g) r[g] = lds[base + (g ^ tl)];
}
__device__ __forceinline__ void x_contig_to_mid(v2f* r, v2f* lds, int t){
    int tl = t & 15, base = 16*t;
#pragma unroll
    for (int g = 0; g < 16; ++g) lds[base + (g ^ tl)] = r[g];
    __syncthreads();
    int Bq = (t >> 4) * 256, c = t & 15;
#pragma unroll
    for (int g = 0; g < 16; ++g) r[g] = lds[Bq + 16*g + (c ^ g)];
}
__device__ __forceinline__ void x_mid_to_strided(v2f* r, v2f* lds, int t){
    int Bq = (t >> 4) * 256, c = t & 15;
#pragma unroll
    for (int g = 0; g < 16; ++g) lds[Bq + 16*g + (c ^ g)] = r[g];
    __syncthreads();
    int tsw = t ^ (t >> 4);
#pragma unroll
    for (int q = 0; q < 16; ++q) r[q] = lds[256*q + tsw];
}
// dual-chain, time-shared 32 KiB buffer: writeA,bar,readA,bar,writeB,bar,readB.
// Chaining invariant: next exchange's write-set == this thread's last read-set.
__device__ __forceinline__ void x2_strided_to_mid(v2f* ra, v2f* rb, v2f* lds, int t){
    int tsw = t ^ (t >> 4);
    int Bq = (t >> 4) * 256, c = t & 15;
#pragma unroll
    for (int q = 0; q < 16; ++q) lds[256*q + tsw] = ra[q];
    __syncthreads();
#pragma unroll
    for (int g = 0; g < 16; ++g) ra[g] = lds[Bq + 16*g + (c ^ g)];
    __syncthreads();
#pragma unroll
    for (int q = 0; q < 16; ++q) lds[256*q + tsw] = rb[q];
    __syncthreads();
#pragma unroll
    for (int g = 0; g < 16; ++g) rb[g] = lds[Bq + 16*g + (c ^ g)];
}
__device__ __forceinline__ void x2_mid_to_contig(v2f* ra, v2f* rb, v2f* lds, int t){
    int Bq = (t >> 4) * 256, c = t & 15;
    int tl = t & 15, base = 16*t;
#pragma unroll
    for (int g = 0; g < 16; ++g) lds[Bq + 16*g + (c ^ g)] = ra[g];
    __syncthreads();
#pragma unroll
    for (int g = 0; g < 16; ++g) ra[g] = lds[base + (g ^ tl)];
    __syncthreads();
#pragma unroll
    for (int g = 0; g < 16; ++g) lds[Bq + 16*g + (c ^ g)] = rb[g];
    __syncthreads();
#pragma unroll
    for (int g = 0; g < 16; ++g) rb[g] = lds[base + (g ^ tl)];
}
__device__ __forceinline__ void x2_contig_to_mid(v2f* ra, v2f* rb, v2f* lds, int t){
    int tl = t & 15, base = 16*t;
    int Bq = (t >> 4) * 256, c = t & 15;
#pragma unroll
    for (int g = 0; g < 16; ++g) lds[base + (g ^ tl)] = ra[g];
    __syncthreads();
#pragma unroll
    for (int g = 0; g < 16; ++g) ra[g] = lds[Bq + 16*g + (c ^ g)];
    __syncthreads();
#pragma unroll
    for (int g = 0; g < 16; ++g) lds[base + (g ^ tl)] = rb[g];
    __syncthreads();
#pragma unroll
    for (int g = 0; g < 16; ++g) rb[g] = lds[Bq + 16*g + (c ^ g)];
}
__device__ __forceinline__ void x2_mid_to_strided(v2f* ra, v2f* rb, v2f* lds, int t){
    int Bq = (t >> 4) * 256, c = t & 15;
    int tsw = t ^ (t >> 4);
#pragma unroll
    for (int g = 0; g < 16; ++g) lds[Bq + 16*g + (c ^ g)] = ra[g];
    __syncthreads();
#pragma unroll
    for (int q = 0; q < 16; ++q) ra[q] = lds[256*q + tsw];
    __syncthreads();
#pragma unroll
    for (int g = 0; g < 16; ++g) lds[Bq + 16*g + (c ^ g)] = rb[g];
    __syncthreads();
#pragma unroll
    for (int q = 0; q < 16; ++q) rb[q] = lds[256*q + tsw];
}

// ------- setup: spline tridiag solve (blocks 0-7) + twiddles (blocks 8-13) --
// twiddles: fp64-generated (HW-trig version regressed absmax to 1.7e-3, r14)
__global__ __launch_bounds__(256) void k_setup(const float* __restrict__ p,
        float* __restrict__ Mv, v2f* __restrict__ tw1,
        v2f* __restrict__ tw2, v2f* __restrict__ tw3){
    int bid = blockIdx.x;
    int t = threadIdx.x;
    if (bid >= 8){
        int idx = (bid - 8) * 256 + t;
        if (idx >= 1360) return;
        int m, L;
        if (idx < 1024)      { m = idx;        L = 4096; }
        else if (idx < 1280) { m = idx - 1024; L = 1024; }
        else if (idx < 1344) { m = idx - 1280; L = 256;  }
        else                 { m = idx - 1344; L = 64;   }
        double ang = -2.0 * dPI * (double)m / (double)L;
        double s1, c1, s2, c2v, s3, c3;
        sincos(ang, &s1, &c1);
        sincos(2.0*ang, &s2, &c2v);
        sincos(3.0*ang, &s3, &c3);
        tw1[idx] = mkv((float)c1,  (float)s1);
        tw2[idx] = mkv((float)c2v, (float)s2);
        tw3[idx] = mkv((float)c3,  (float)s3);
        return;
    }
    __shared__ float sY[328];
    int B0 = bid * 256;
    for (int k = t; k < 324; k += 256){
        int jg = B0 - 32 + k;                 // Y[j] = j<1024 ? p[j>>1] : 0
        sY[k] = (jg >= 0 && jg < 1024) ? p[jg >> 1] : 0.0f;
    }
    __syncthreads();
    int i = B0 + t;
    if (i >= 2046) return;
    auto rhs = [&](int j) -> float {
        if (j < 0 || j >= 2046) return 0.0f;
        int l = j - B0 + 32;
        return 6.0f * (sY[l+2] - 2.0f*sY[l+1] + sY[l]);
    };
    float x = TRI_C * rhs(i);
    float wd = TRI_C;
    for (int d = 1; d <= 32; ++d){
        wd *= TRI_R;
        x += wd * (rhs(i-d) + rhs(i+d));
    }
    if (i < 48){
        float cA = 0.0f, wj = TRI_C;
        for (int j = 0; j < 32; ++j){ wj *= TRI_R; cA += wj * rhs(j); }
        float rp = 1.0f;
        for (int k = 0; k <= i; ++k) rp *= TRI_R;
        x -= cA * rp;
    }
    if (i >= 1998){
        float cB = 0.0f, wj = TRI_C;
        for (int j = 0; j < 32; ++j){ wj *= TRI_R; cB += wj * rhs(2045 - j); }
        float rp = 1.0f;
        for (int k = 0; k < 2046 - i; ++k) rp *= TRI_R;
        x -= cB * rp;
    }
    Mv[i+1] = x;
    if (i == 0)    Mv[0]    = 0.0f;
    if (i == 2045) Mv[2047] = 0.0f;
}

// ---------------- pass 1: field build + fwd row FFT (fp16 out) --------------
__global__ __launch_bounds__(256) void k_pass1(const float* __restrict__ p,
        const float* __restrict__ Mv,
        const v2f* __restrict__ tw1, const v2f* __restrict__ tw2,
        const v2f* __restrict__ tw3, h2f* __restrict__ F1){
    __shared__ v2f lds[4096];
    float* ldsf = (float*)lds;
    int t = threadIdx.x;
    int row = blockIdx.x;                 // y = 1024 + row
    v2f r[16];
    // stage spline tables in LDS (buffer free until first exchange)
    for (int j = t; j < 512; j += 256)  ldsf[j] = p[j];
    for (int j = t; j < 2048; j += 256) ldsf[512 + j] = Mv[j];
    __syncthreads();
    int y = 1024 + row;
    int iy = row;
    int a = (iy < 1024) ? (1023 - iy) : (iy - 1024);
    float fy = PITCHF * (float)(y - 2048);
    float cy2 = fy * fy;
    float af = (float)a + 0.5f;
#pragma unroll
    for (int q = 4; q < 12; ++q){
        int x = t + 256*q;                // in [1024, 3072)
        int ix = x - 1024;
        int b = (ix < 1024) ? (1023 - ix) : (ix - 1024);
        float bf = (float)b + 0.5f;
        float rq = sqrtf(af*af + bf*bf);
        int ind = (int)rq; if (ind > 2046) ind = 2046;
        float tt = rq - (float)ind;
        float y0v = (ind < 1024) ? ldsf[ind >> 1] : 0.0f;        // Y[ind]
        float y1v = (ind + 1 < 1024) ? ldsf[(ind + 1) >> 1] : 0.0f; // Y[ind+1]
        float m0 = ldsf[512 + ind], m1 = ldsf[512 + ind + 1];
        float bb = (y1v - y0v) - (2.0f*m0 + m1) / 6.0f;
        float bias = y0v + tt*(bb + tt*(m0/2.0f + tt*(m1-m0)/6.0f));
        float fx = PITCHF * (float)(x - 2048);
        float r2 = fx*fx + cy2;
        float ip = C1F * r2;
        float lp = -((KFF * r2) / TWO_FOCAL_F);
        float sp = ip + lp + bias;
        float fv = sp * INV_TPF;                     // phase in revolutions
        float fr = fv - floorf(fv);                  // [0,1)
        float sn = __builtin_amdgcn_sinf(fr);
        float cs = __builtin_amdgcn_cosf(fr);
        r[q] = mkv(cs, sn);
    }
    __syncthreads();                      // staged-table reads done
    front_fwd<true>(r, t, tw1, tw2, tw3);
    x_strided_to_mid(r, lds, t);
    mid_fwd(r, t & 15, tw1, tw2, tw3);
    x_mid_to_contig(r, lds, t);
    tail_fwd(r);
    size_t base = (size_t)row * 4096;
#pragma unroll
    for (int g = 0; g < 16; ++g)
        F1[base + 256*g + t] = toh(r[g]);  // coalesced per g
}

// ------- tiled 4-byte transpose, uint4-vectorized 64x64 tiles ---------------
__global__ __launch_bounds__(256) void k_transpose_h(const unsigned* __restrict__ in,
                                                     unsigned* __restrict__ out,
                                                     int H, int W){
    __shared__ unsigned tile[64][65];
    int bx = blockIdx.x * 64, by = blockIdx.y * 64;  // bx: W dim, by: H dim
    int tx = threadIdx.x, ty = threadIdx.y;   // (16,16)
#pragma unroll
    for (int k = 0; k < 4; ++k){
        int rr = by + ty + 16*k;          // H always multiple of 64
        int cc = bx + 4*tx;
        if (cc + 3 < W){
            uint4 v = *(const uint4*)&in[(size_t)rr * W + cc];
            tile[ty+16*k][4*tx+0] = v.x;
            tile[ty+16*k][4*tx+1] = v.y;
            tile[ty+16*k][4*tx+2] = v.z;
            tile[ty+16*k][4*tx+3] = v.w;
        } else {
#pragma unroll
            for (int j = 0; j < 4; ++j)
                if (cc + j < W) tile[ty+16*k][4*tx+j] = in[(size_t)rr * W + cc + j];
        }
    }
    __syncthreads();
#pragma unroll
    for (int k = 0; k < 4; ++k){
        int rr = bx + ty + 16*k;
        int cc = by + 4*tx;               // always < H
        if (rr < W){
            uint4 v;
            v.x = tile[4*tx+0][ty+16*k];
            v.y = tile[4*tx+1][ty+16*k];
            v.z = tile[4*tx+2][ty+16*k];
            v.w = tile[4*tx+3][ty+16*k];
            *(uint4*)&out[(size_t)rr * H + cc] = v;
        }
    }
}

// ------- pass 2: dual-chain (2 columns/thread), time-shared 32 KiB LDS ------
__global__ __launch_bounds__(256) void k_pass2(const h2f* __restrict__ F1T,
        const v2f* __restrict__ tw1, const v2f* __restrict__ tw2,
        const v2f* __restrict__ tw3, h2f* __restrict__ GT){
    __shared__ v2f lds[4096];             // 32 KiB, time-shared between chains
    int t = threadIdx.x;
    int cp0 = 2 * blockIdx.x, cp1 = cp0 + 1;
    v2f ra[16], rb[16];
    size_t base0 = (size_t)cp0 * 2048;
    size_t base1 = (size_t)cp1 * 2048;
#pragma unroll
    for (int q = 4; q < 12; ++q){
        ra[q] = tof(F1T[base0 + t + 256*(q-4)]);
        rb[q] = tof(F1T[base1 + t + 256*(q-4)]);
    }
    front_fwd2<true>(ra, rb, t, tw1, tw2, tw3);
    x2_strided_to_mid(ra, rb, lds, t);
    mid_fwd2(ra, rb, t & 15, tw1, tw2, tw3);
    x2_mid_to_contig(ra, rb, lds, t);
    tail_fwd(ra); tail_fwd(rb);
    // ---- H multiply in digit-reversed frequency domain (incl. 1/N^2) ----
    int pcol0 = ((cp0 & 255) << 4) | (cp0 >> 8);
    int pcol1 = ((cp1 & 255) << 4) | (cp1 >> 8);
    int kxs0 = (digitrev12(pcol0) + 2048) & 4095;
    int kxs1 = (digitrev12(pcol1) + 2048) & 4095;
    float fxv0 = ((float)(kxs0 + 1) - 2048.0f) / SENSOR_DF;
    float fxv1 = ((float)(kxs1 + 1) - 2048.0f) / SENSOR_DF;
    float fx20 = fxv0 * fxv0;
    float fx21 = fxv1 * fxv1;
    int rt = __brev((unsigned)t) >> 24;
    rt = ((rt & 0x55) << 1) | ((rt >> 1) & 0x55);   // 4-digit base-4 reversal of t
#pragma unroll
    for (int g = 0; g < 16; ++g){
        const int rg = ((g & 3) << 2) | (g >> 2);
        int ky = rg * 256 + rt;                      // digitrev12(16 t + g)
        int kys = (ky + 2048) & 4095;
        float fyv = ((float)(kys + 1) - 2048.0f) / SENSOR_DF;
        float fy2 = fyv * fyv;
        {   float arg = fmaxf(ILAM2F - fx20 - fy2, 0.0f);
            float Hp = (TPF * sqrtf(arg)) * D2F;
            float v  = Hp * INV_TPF;
            float nn = rintf(v);
            float rr2 = fmaf(nn, -TPH, Hp);
            rr2       = fmaf(nn, -TPL, rr2);
            float rev = rr2 * INV_TPF;
            float sn = __builtin_amdgcn_sinf(rev);
            float cs = __builtin_amdgcn_cosf(rev);
            ra[g] = cmul(ra[g], mkv(cs * SCALE, sn * SCALE));
        }
        {   float arg = fmaxf(ILAM2F - fx21 - fy2, 0.0f);
            float Hp = (TPF * sqrtf(arg)) * D2F;
            float v  = Hp * INV_TPF;
            float nn = rintf(v);
            float rr2 = fmaf(nn, -TPH, Hp);
            rr2       = fmaf(nn, -TPL, rr2);
            float rev = rr2 * INV_TPF;
            float sn = __builtin_amdgcn_sinf(rev);
            float cs = __builtin_amdgcn_cosf(rev);
            rb[g] = cmul(rb[g], mkv(cs * SCALE, sn * SCALE));
        }
    }
    head_inv(ra); head_inv(rb);
    x2_contig_to_mid(ra, rb, lds, t);
    mid_inv2(ra, rb, t & 15, tw1, tw2, tw3);
    x2_mid_to_strided(ra, rb, lds, t);
    v2f oa[4], ob[4];
    back_inv_crop2(ra, rb, t, tw1, tw2, tw3, oa, ob);
    size_t ob0 = (size_t)cp0 * 728;
    size_t ob1 = (size_t)cp1 * 728;
    // crop y in [1685, 2413): idx = t + 256q - 1685, q=6..9 -> oa[0..3]
    if (t >= 149){ GT[ob0 + t - 149] = toh(oa[0]); GT[ob1 + t - 149] = toh(ob[0]); }
    GT[ob0 + t + 107] = toh(oa[1]); GT[ob1 + t + 107] = toh(ob[1]);
    GT[ob0 + t + 363] = toh(oa[2]); GT[ob1 + t + 363] = toh(ob[2]);
    if (t < 109){ GT[ob0 + t + 619] = toh(oa[3]); GT[ob1 + t + 619] = toh(ob[3]); }
}

// ---------------- pass 3: inv row FFT on crop rows, |.|^2 -------------------
__global__ __launch_bounds__(256, 8) void k_pass3(const h2f* __restrict__ G,
        float* __restrict__ out, float* __restrict__ partials,
        const v2f* __restrict__ tw1, const v2f* __restrict__ tw2,
        const v2f* __restrict__ tw3){
    __shared__ v2f lds[4096];
    int t = threadIdx.x;
    int row = blockIdx.x;
    v2f r[16];
    size_t base = (size_t)row * 4096;
#pragma unroll
    for (int g = 0; g < 16; ++g)
        r[g] = tof(G[base + 256*g + t]);  // c' = 256 g + t <-> p = 16 t + g
    head_inv(r);
    x_contig_to_mid(r, lds, t);
    mid_inv(r, t & 15, tw1, tw2, tw3);
    x_mid_to_strided(r, lds, t);
    v2f o6, o7, o8, o9;
    back_inv_crop(r, t, tw1, tw2, tw3, o6, o7, o8, o9);
    float lsum = 0.0f;
    size_t ob = (size_t)row * 728;
    if (t >= 149){ float I = o6.x*o6.x + o6.y*o6.y; out[ob + t - 149] = I; lsum += I; }
    { float I = o7.x*o7.x + o7.y*o7.y; out[ob + t + 107] = I; lsum += I; }
    { float I = o8.x*o8.x + o8.y*o8.y; out[ob + t + 363] = I; lsum += I; }
    if (t < 109){ float I = o9.x*o9.x + o9.y*o9.y; out[ob + t + 619] = I; lsum += I; }
    __syncthreads();                       // all exchange reads done
    float* red = (float*)lds;
    red[t] = lsum;
    __syncthreads();
    for (int k2 = 128; k2 > 0; k2 >>= 1){
        if (t < k2) red[t] += red[t + k2];
        __syncthreads();
    }
    if (t == 0) partials[row] = red[0];
}

// ---------------- normalize (per-block redundant deterministic reduce) ------
__global__ __launch_bounds__(256) void k_norm(float* __restrict__ out,
                                              const float* __restrict__ partials,
                                              int n){
    __shared__ float red[256];
    int t = threadIdx.x;
    float s = 0.0f;
    for (int i = t; i < 728; i += 256) s += partials[i];
    red[t] = s;
    __syncthreads();
    for (int k = 128; k > 0; k >>= 1){
        if (t < k) red[t] += red[t + k];
        __syncthreads();
    }
    float total = red[0];
    int i = blockIdx.x * 256 + t;
    if (i < n) out[i] = out[i] / total;
}

// ---------------- launch ----------------
extern "C" void kernel_launch(void* const* d_in, const int* in_sizes, int n_in,
                              void* d_out, int out_size, void* d_ws, size_t ws_size,
                              hipStream_t stream) {
    const float* p   = (const float*)d_in[0];
    float*       out = (float*)d_out;
    char*        ws  = (char*)d_ws;

    float* Mv       = (float*)(ws + 8192);         // 2048 f
    float* partials = (float*)(ws + 16384);        // 728 f
    v2f*   tw1      = (v2f*)(ws + 24576);          // 1360 c (fp32)
    v2f*   tw2      = (v2f*)(ws + 40960);
    v2f*   tw3      = (v2f*)(ws + 57344);

    const size_t BIG = (size_t)64 * 1024 * 1024;
    h2f* F1  = (h2f*)(ws + (1 << 20));             // [2048][4096] fp16c, 32MB
    h2f* F1T = (h2f*)(ws + (1 << 20) + BIG);       // [4096][2048] fp16c
    h2f* GT  = F1;                                  // reuse: [4096][728]
    h2f* G   = F1T;                                 // reuse: [728][4096]

    k_setup<<<14, 256, 0, stream>>>(p, Mv, tw1, tw2, tw3);
    k_pass1<<<2048, 256, 0, stream>>>(p, Mv, tw1, tw2, tw3, F1);
    k_transpose_h<<<dim3(64, 32), dim3(16, 16), 0, stream>>>((const unsigned*)F1, (unsigned*)F1T, 2048, 4096);
    k_pass2<<<2048, 256, 0, stream>>>(F1T, tw1, tw2, tw3, GT);
    k_transpose_h<<<dim3(12, 64), dim3(16, 16), 0, stream>>>((const unsigned*)GT, (unsigned*)G, 4096, 728);
    k_pass3<<<728, 256, 0, stream>>>(G, out, partials, tw1, tw2, tw3);
    int n = out_size;
    k_norm<<<(n + 255) / 256, 256, 0, stream>>>(out, partials, n);
}